// Round 5
// baseline (282.249 us; speedup 1.0000x reference)
//
#include <hip/hip_runtime.h>

// Round 14: barrier-free fragment-direct GEMMs.
// Post-mortem r13: occupancy 23->45% bought only 77->67 us; the 2-phase
// barrier+LDS-roundtrip loop is the structural floor (cf. m233: ~72% overhead;
// m99-m141: untunable). This round removes the structure instead of tuning it:
// - W (and y, and wo) are pre-permuted into MFMA-fragment order
//   [grp32][kslice16][lane64][8 f16]: a wave fetches a fragment with ONE
//   coalesced 16B/lane global load. No LDS, no ds_read, no barrier for these.
// - A (fp32 q/k/v) is cvt'd+transposed through WAVE-PRIVATE LDS (4 KB/wave
//   ping-pong, same-wave write->read, compiler lgkmcnt, zero barriers).
// - Hot loop = {coalesced loads + 4 MFMA}, 2-deep named-reg prefetch
//   (rule-20 safe), compiler-scheduled waits. No inter-wave coupling at all.
// - Block = 4 waves (2m x 2n) sharing W/A lines via L1; grids colocate
//   same-bm blocks on one XCD (flat ids differ by multiples of 8).
// - attn unchanged except y now stored in fragment order for gemm_out.

using f16    = _Float16;
using f16x4  = __attribute__((ext_vector_type(4))) _Float16;
using f16x8  = __attribute__((ext_vector_type(8))) _Float16;
using f32x4  = __attribute__((ext_vector_type(4))) float;
using f32x16 = __attribute__((ext_vector_type(16))) float;

static constexpr int S = 1024, Dm = 1024, NH = 16, HD = 64;

#if __has_builtin(__builtin_amdgcn_mfma_f32_32x32x16_f16)
#define USE_G32 1
#define MFMA32(ACC, A_, B_) \
    (ACC) = __builtin_amdgcn_mfma_f32_32x32x16_f16((A_), (B_), (ACC), 0, 0, 0)
#else
#define USE_G32 0
#endif

#if __has_builtin(__builtin_amdgcn_mfma_f32_16x16x32_f16) && \
    __has_builtin(__builtin_amdgcn_mfma_f32_16x16x16f16)
#define USE_A16 1
#define MFMA16K32(ACC, A_, B_) \
    (ACC) = __builtin_amdgcn_mfma_f32_16x16x32_f16((A_), (B_), (ACC), 0, 0, 0)
#define MFMA16(ACC, A_, B_) \
    (ACC) = __builtin_amdgcn_mfma_f32_16x16x16f16((A_), (B_), (ACC), 0, 0, 0)
#else
#define USE_A16 0
#endif

#define LO4(v) __builtin_shufflevector((v), (v), 0, 1, 2, 3)
#define HI4(v) __builtin_shufflevector((v), (v), 4, 5, 6, 7)

__device__ __forceinline__ f16x4 cvt4(float4 a) {
    f16x4 r; r[0] = (f16)a.x; r[1] = (f16)a.y; r[2] = (f16)a.z; r[3] = (f16)a.w;
    return r;
}

// hd permutation for qh/kh (K=32 QK MFMA), unchanged (verified round 10).
__device__ __forceinline__ int pcol64(int k) {
#if USE_A16
    return ((k >> 3) & 3) * 16 + ((k >> 5) << 3) + (k & 7);
#else
    return ((k >> 2) & 3) * 16 + ((k >> 4) << 2) + (k & 3);
#endif
}

// Fragment-order index for a [rows][1024] f16 matrix:
// unit = [rgrp=r>>5][ks=k>>4][lane=(r&31)+32*((k>>3)&1)][elem=k&7]
// MFMA frag load for (rgrp, ks) = ONE 16B/lane coalesced read at lane*16B.
__device__ __forceinline__ size_t fidx(int r, int k) {
    return ((size_t)((r >> 5) * 64 + (k >> 4)) * 64
            + (r & 31) + ((k >> 3) & 1) * 32) * 8 + (k & 7);
}

// mode 0: [B,H,S,HD] f16 hd-permuted; 1: [B,H,HD,S] f16
__device__ __forceinline__ void store_out(void* out, int mode, int m, int n, float v) {
    const int b_ = m >> 10, s_ = m & 1023, h_ = n >> 6, hd_ = n & 63;
    const size_t idx = (mode == 0)
        ? (((size_t)(b_ * NH + h_) * S + s_) * HD + pcol64(hd_))
        : (((size_t)(b_ * NH + h_) * HD + hd_) * S + s_);
    ((f16*)out)[idx] = (f16)v;
}

// ---------------------------------------------------------------------------
// fp32 W -> f16 in fragment order. grid (512, nmat); one f16x8 per thread.
// ---------------------------------------------------------------------------
__global__ __launch_bounds__(256)
void cvt_w(const float* __restrict__ s0, const float* __restrict__ s1,
           const float* __restrict__ s2, f16* __restrict__ dst)
{
    const int z = blockIdx.y;
    const float* src = (z == 0) ? s0 : (z == 1) ? s1 : s2;
    const int e = blockIdx.x * 256 + threadIdx.x;   // 131072 per matrix
    const int n = e >> 7;
    const int k0 = (e & 127) * 8;
    const float4 v0 = *(const float4*)(src + (size_t)n * Dm + k0);
    const float4 v1 = *(const float4*)(src + (size_t)n * Dm + k0 + 4);
    f16x8 w;
    w[0] = (f16)v0.x; w[1] = (f16)v0.y; w[2] = (f16)v0.z; w[3] = (f16)v0.w;
    w[4] = (f16)v1.x; w[5] = (f16)v1.y; w[6] = (f16)v1.z; w[7] = (f16)v1.w;
    *(f16x8*)&dst[(size_t)z * Dm * Dm + fidx(n, k0)] = w;
}

// ---------------------------------------------------------------------------
// gemm_qkv: out = relu(A @ W^T + b). A fp32 row-major; W f16 fragment-order.
// Block 256 th = 4 waves (2m x 2n), tile 64x128; per-wave 32x64.
// Per iter (BK=32): 4 fp32 A-loads (stage via wave-private LDS) + 4 W frag
// loads + 4 MFMA. No barriers anywhere; 2-deep prefetch, compiler waits.
// 32x32x16 frag: A lane l: A[m=l&31][k=8*(l>>5)+j]; C/D reg i:
// row = 8*(i>>2) + 4*(l>>5) + (i&3), col = l&31 (HW-verified rounds 10-13).
// ---------------------------------------------------------------------------
__global__ __launch_bounds__(256, 4)
void gemm_qkv(const float* __restrict__ q, const float* __restrict__ k,
              const float* __restrict__ v, const f16* __restrict__ wqkv,
              const float* __restrict__ bq, const float* __restrict__ bk,
              const float* __restrict__ bv,
              f16* __restrict__ qh, f16* __restrict__ kh, f16* __restrict__ vt)
{
    const int z = blockIdx.z;
    const float* A = (z == 0) ? q : (z == 1) ? k : v;
    const float* bias = (z == 0) ? bq : (z == 1) ? bk : bv;
    f16* out = (z == 0) ? qh : (z == 1) ? kh : vt;
    const int mode = (z == 2) ? 1 : 0;
    const f16* Wf = wqkv + (size_t)z * Dm * Dm;

    const int tid = threadIdx.x;
    const int bm = blockIdx.x, bn = blockIdx.y;   // (64, 8)
#if USE_G32
    // Wave-private A staging: [wave][buf][kh-half][pos=(r&31)+32*s][8 f16]
    __shared__ alignas(16) f16 Apriv[4][2][2][64][8];   // 16 KB

    const int lane = tid & 63, wave = tid >> 6;
    const int l31 = lane & 31, khh = lane >> 5;
    const int wm = wave & 1, wn = wave >> 1;

    // A fp32 source: lane -> row wm*32 + (lane>>1), 16 floats at (lane&1)*16
    const float* Af = A + (size_t)(bm * 64 + wm * 32 + (lane >> 1)) * Dm
                        + (lane & 1) * 16;
    // W fragment bases (two 32-col groups per wave)
    const f16* Wq0 = Wf + (size_t)(bn * 4 + wn * 2) * 32768 + lane * 8;
    const f16* Wq1 = Wq0 + 32768;

    auto loadA = [&](int t, float4 (&pa)[4]) {
#pragma unroll
        for (int j = 0; j < 4; ++j) pa[j] = *(const float4*)(Af + t * 32 + j * 4);
    };
    auto stage = [&](int buf, const float4 (&pa)[4]) {
        f16x8 lo, hi;
        lo[0] = (f16)pa[0].x; lo[1] = (f16)pa[0].y; lo[2] = (f16)pa[0].z; lo[3] = (f16)pa[0].w;
        lo[4] = (f16)pa[1].x; lo[5] = (f16)pa[1].y; lo[6] = (f16)pa[1].z; lo[7] = (f16)pa[1].w;
        hi[0] = (f16)pa[2].x; hi[1] = (f16)pa[2].y; hi[2] = (f16)pa[2].z; hi[3] = (f16)pa[2].w;
        hi[4] = (f16)pa[3].x; hi[5] = (f16)pa[3].y; hi[6] = (f16)pa[3].z; hi[7] = (f16)pa[3].w;
        const int pos = (lane >> 1) + (lane & 1) * 32;   // r + 32*s
        *(f16x8*)&Apriv[wave][buf][0][pos][0] = lo;
        *(f16x8*)&Apriv[wave][buf][1][pos][0] = hi;
    };
    auto frag = [&](int buf, int s) -> f16x8 {
        return *(const f16x8*)&Apriv[wave][buf][khh][l31 + s * 32][0];
    };
    auto loadW = [&](int t, f16x8 (&w)[4]) {
        const f16* p0 = Wq0 + (size_t)t * 1024;   // ks0 = 2t -> 2t*512 f16
        const f16* p1 = Wq1 + (size_t)t * 1024;
        w[0] = *(const f16x8*)p0;
        w[1] = *(const f16x8*)(p0 + 512);
        w[2] = *(const f16x8*)p1;
        w[3] = *(const f16x8*)(p1 + 512);
    };

    f32x16 acc0 = {}, acc1 = {};
    constexpr int NIT = Dm / 32;   // 32

    float4 a0[4], a1[4];
    f16x8  w0[4], w1[4];
    loadA(0, a0); loadW(0, w0);
    loadA(1, a1); loadW(1, w1);
    stage(0, a0);                  // tile 0 -> buf 0 (waits a0 only)

    auto body = [&](int t, float4 (&aD)[4], float4 (&aS)[4], f16x8 (&wU)[4]) {
        const int rb = t & 1;
        const f16x8 f0 = frag(rb, 0);
        const f16x8 f1 = frag(rb, 1);
        if (t + 2 < NIT) loadA(t + 2, aD);       // early issue; aD's tile staged
        MFMA32(acc0, f0, wU[0]);
        MFMA32(acc1, f0, wU[2]);
        MFMA32(acc0, f1, wU[1]);
        MFMA32(acc1, f1, wU[3]);
        if (t + 1 < NIT) stage((t + 1) & 1, aS); // tile t+1 -> other buf
        if (t + 2 < NIT) loadW(t + 2, wU);       // after last use of wU
    };

    for (int t = 0; t < NIT; t += 2) {
        body(t,     a0, a1, w0);
        body(t + 1, a1, a0, w1);
    }

    // epilogue (C/D map verified rounds 10-13)
#pragma unroll
    for (int j = 0; j < 2; ++j) {
        const int col = bn * 128 + wn * 64 + j * 32 + l31;
        const float bb = bias[col];
        const f32x16& ac = j ? acc1 : acc0;
#pragma unroll
        for (int blk = 0; blk < 4; ++blk) {
            const int row0 = bm * 64 + wm * 32 + 8 * blk + 4 * khh;
            if (mode == 1) {   // [B,H,HD,S]: 4 consecutive s -> packed b64
                const int b_ = row0 >> 10, s_ = row0 & 1023;
                const int h_ = col >> 6, hd_ = col & 63;
                f16x4 vv;
#pragma unroll
                for (int r = 0; r < 4; ++r)
                    vv[r] = (f16)fmaxf(ac[blk * 4 + r] + bb, 0.0f);
                *(f16x4*)&out[((size_t)(b_ * NH + h_) * HD + hd_) * S + s_] = vv;
            } else {
#pragma unroll
                for (int r = 0; r < 4; ++r)
                    store_out(out, mode, row0 + r, col,
                              fmaxf(ac[blk * 4 + r] + bb, 0.0f));
            }
        }
    }
#else
    for (int i = tid; i < 64 * 128; i += 256) {
        const int m = bm * 64 + (i >> 7);
        const int n = bn * 128 + (i & 127);
        float acc = 0.0f;
        for (int k2 = 0; k2 < Dm; ++k2)
            acc = fmaf(A[(size_t)m * Dm + k2], (float)Wf[fidx(n, k2)], acc);
        store_out(out, mode, m, n, fmaxf(acc + bias[n], 0.0f));
    }
#endif
}

// ---------------------------------------------------------------------------
// gemm_out: out = relu(y @ Wo^T + b), fp32 out. y and wo BOTH fragment-order
// f16 -> pure load+MFMA, zero LDS, zero barriers. Block 4 waves (2m x 2n),
// per-wave 32x32, grid (64, 16) = 1024 blocks.
// ---------------------------------------------------------------------------
__global__ __launch_bounds__(256, 4)
void gemm_out(const f16* __restrict__ y, const f16* __restrict__ wo,
              const float* __restrict__ bo, float* __restrict__ out)
{
    const int tid = threadIdx.x;
    const int bm = blockIdx.x, bn = blockIdx.y;   // (64, 16)
#if USE_G32
    const int lane = tid & 63, wave = tid >> 6;
    const int l31 = lane & 31, khh = lane >> 5;
    const int wm = wave & 1, wn = wave >> 1;

    const f16* Ab = y  + (size_t)(bm * 2 + wm) * 32768 + lane * 8;
    const f16* Wb = wo + (size_t)(bn * 2 + wn) * 32768 + lane * 8;

    auto la = [&](int t, f16x8 (&a)[2]) {
        a[0] = *(const f16x8*)(Ab + (size_t)t * 1024);
        a[1] = *(const f16x8*)(Ab + (size_t)t * 1024 + 512);
    };
    auto lw = [&](int t, f16x8 (&w)[2]) {
        w[0] = *(const f16x8*)(Wb + (size_t)t * 1024);
        w[1] = *(const f16x8*)(Wb + (size_t)t * 1024 + 512);
    };

    f32x16 acc = {};
    constexpr int NIT = Dm / 32;   // 32
    f16x8 a0[2], a1[2], w0[2], w1[2];
    la(0, a0); lw(0, w0);
    la(1, a1); lw(1, w1);

    auto body = [&](int t, f16x8 (&aU)[2], f16x8 (&wU)[2]) {
        MFMA32(acc, aU[0], wU[0]);
        MFMA32(acc, aU[1], wU[1]);
        if (t + 2 < NIT) { la(t + 2, aU); lw(t + 2, wU); }
    };
    for (int t = 0; t < NIT; t += 2) {
        body(t, a0, w0);
        body(t + 1, a1, w1);
    }

    const int col = bn * 64 + wn * 32 + l31;
    const float bb = bo[col];
#pragma unroll
    for (int blk = 0; blk < 4; ++blk) {
        const int row0 = bm * 64 + wm * 32 + 8 * blk + 4 * khh;
#pragma unroll
        for (int r = 0; r < 4; ++r)
            out[(size_t)(row0 + r) * Dm + col] = fmaxf(acc[blk * 4 + r] + bb, 0.0f);
    }
#else
    for (int i = tid; i < 64 * 64; i += 256) {
        const int m = bm * 64 + (i >> 6);
        const int n = bn * 64 + (i & 63);
        float acc = 0.0f;
        for (int k2 = 0; k2 < Dm; ++k2)
            acc = fmaf((float)y[fidx(m, k2)], (float)wo[fidx(n, k2)], acc);
        out[(size_t)m * Dm + n] = fmaxf(acc + bo[n], 0.0f);
    }
#endif
}

// ---------------------------------------------------------------------------
// Flash attention — unchanged since round 10 (passing) EXCEPT: y is stored in
// fragment order (fidx) so gemm_out can fragment-load it directly.
// ---------------------------------------------------------------------------
__global__ __launch_bounds__(256)
void attn_fwd(const f16* __restrict__ qh, const f16* __restrict__ kh,
              const f16* __restrict__ vt, f16* __restrict__ y)
{
    const int bz = blockIdx.x;       // B*H*(S/64) = 1024
    const int qt = bz & 15;
    const int h  = (bz >> 4) & 15;
    const int b  = bz >> 8;
    const size_t head = (size_t)(b * NH + h) * S * HD;

#if USE_A16
    __shared__ alignas(16) f16 Ks[2][64][72];
    __shared__ alignas(16) f16 Vs[2][64][72];

    const int tid  = threadIdx.x;
    const int wave = tid >> 6;
    const int lane = tid & 63;
    const int l15  = lane & 15;
    const int quad = lane >> 4;
    const int sr   = tid >> 2;
    const int sc   = (tid & 3) * 16;

    const f16* Qrow = qh + head + (size_t)(qt * 64 + wave * 16 + l15) * HD;
    const f16* Kp   = kh + head;
    const f16* Vp   = vt + head;

    f16x8 aq[2];
    {
        const uint4 q0 = *(const uint4*)(Qrow + quad * 16);
        const uint4 q1 = *(const uint4*)(Qrow + quad * 16 + 8);
        aq[0] = *(f16x8*)&q0;
        aq[1] = *(f16x8*)&q1;
    }

    const int qg = qt * 64 + wave * 16 + l15;
    float m_i = -1e30f, l_i = 0.0f;
    f32x4 acc_o[4] = {};

    uint4 pk[2], pv[2];
    auto pref = [&](int kt) {
        const f16* Kr = Kp + (size_t)(kt * 64 + sr) * HD + sc;
        pk[0] = *(const uint4*)Kr;
        pk[1] = *(const uint4*)(Kr + 8);
        const f16* Vr = Vp + (size_t)sr * S + kt * 64 + sc;
        pv[0] = *(const uint4*)Vr;
        pv[1] = *(const uint4*)(Vr + 8);
    };

    pref(0);
    for (int kt = 0; kt <= qt; ++kt) {
        const int cur = kt & 1;
        *(uint4*)&Ks[cur][sr][sc]     = pk[0];
        *(uint4*)&Ks[cur][sr][sc + 8] = pk[1];
        {
            const int sb = (sc >> 4) * 4;
            *(f16x4*)&Vs[cur][sr][0 * 16 + sb] = *(f16x4*)((f16*)&pv[0]);
            *(f16x4*)&Vs[cur][sr][1 * 16 + sb] = *(f16x4*)((f16*)&pv[0] + 4);
            *(f16x4*)&Vs[cur][sr][2 * 16 + sb] = *(f16x4*)((f16*)&pv[1]);
            *(f16x4*)&Vs[cur][sr][3 * 16 + sb] = *(f16x4*)((f16*)&pv[1] + 4);
        }
        __syncthreads();
        if (kt < qt) pref(kt + 1);

        f32x4 accs[4] = {};
#pragma unroll
        for (int t = 0; t < 4; ++t) {
            const f16x8 k8a = *(const f16x8*)&Ks[cur][t * 16 + l15][quad * 16];
            const f16x8 k8b = *(const f16x8*)&Ks[cur][t * 16 + l15][quad * 16 + 8];
            MFMA16K32(accs[t], k8a, aq[0]);
            MFMA16K32(accs[t], k8b, aq[1]);
        }

        const int key0 = kt * 64 + quad * 4;
#pragma unroll
        for (int t = 0; t < 4; ++t)
#pragma unroll
            for (int r = 0; r < 4; ++r) {
                float sv = accs[t][r] * 0.125f;
                if (key0 + t * 16 + r > qg) sv = -1e9f;
                accs[t][r] = sv;
            }

        float mx = accs[0][0];
#pragma unroll
        for (int t = 0; t < 4; ++t)
#pragma unroll
            for (int r = 0; r < 4; ++r) mx = fmaxf(mx, accs[t][r]);
        mx = fmaxf(mx, __shfl_xor(mx, 16, 64));
        mx = fmaxf(mx, __shfl_xor(mx, 32, 64));
        const float mnew = fmaxf(m_i, mx);
        float sm = 0.0f;
#pragma unroll
        for (int t = 0; t < 4; ++t)
#pragma unroll
            for (int r = 0; r < 4; ++r) {
                const float e = __expf(accs[t][r] - mnew);
                accs[t][r] = e;
                sm += e;
            }
        sm += __shfl_xor(sm, 16, 64);
        sm += __shfl_xor(sm, 32, 64);
        const float alpha = __expf(m_i - mnew);
        l_i = l_i * alpha + sm;
        m_i = mnew;

        f16x4 ap[4];
#pragma unroll
        for (int c = 0; c < 4; ++c) {
            f16x4 v;
#pragma unroll
            for (int j = 0; j < 4; ++j) v[j] = (f16)accs[c][j];
            ap[c] = v;
        }

        float ar[4];
#pragma unroll
        for (int r = 0; r < 4; ++r) ar[r] = __shfl(alpha, quad * 4 + r, 64);
#pragma unroll
        for (int t2 = 0; t2 < 4; ++t2)
#pragma unroll
            for (int r = 0; r < 4; ++r) acc_o[t2][r] *= ar[r];
#pragma unroll
        for (int t2 = 0; t2 < 4; ++t2) {
            const f16x8 v8a = *(const f16x8*)&Vs[cur][t2 * 16 + l15][quad * 16];
            const f16x8 v8b = *(const f16x8*)&Vs[cur][t2 * 16 + l15][quad * 16 + 8];
            MFMA16(acc_o[t2], ap[0], LO4(v8a));
            MFMA16(acc_o[t2], ap[1], HI4(v8a));
            MFMA16(acc_o[t2], ap[2], LO4(v8b));
            MFMA16(acc_o[t2], ap[3], HI4(v8b));
        }
    }

    float lr[4];
#pragma unroll
    for (int r = 0; r < 4; ++r) lr[r] = __shfl(l_i, quad * 4 + r, 64);
#pragma unroll
    for (int t2 = 0; t2 < 4; ++t2)
#pragma unroll
        for (int r = 0; r < 4; ++r) {
            const int srow = qt * 64 + wave * 16 + quad * 4 + r;
            const int dcol = h * 64 + t2 * 16 + l15;
            y[fidx(b * S + srow, dcol)] = (f16)(acc_o[t2][r] / lr[r]);
        }
#else
    const int tid = threadIdx.x;
    if (tid < 64) {
        const int q = qt * 64 + tid;
        const f16* Qr = qh + head + (size_t)q * HD;
        float qv[64];
        for (int d = 0; d < 64; ++d) qv[d] = (float)Qr[pcol64(d)];
        float mx = -1e30f;
        for (int key = 0; key <= q; ++key) {
            const f16* Kr = kh + head + (size_t)key * HD;
            float s = 0.0f;
            for (int d = 0; d < 64; ++d) s = fmaf(qv[d], (float)Kr[pcol64(d)], s);
            mx = fmaxf(mx, s * 0.125f);
        }
        float o[64];
        for (int d = 0; d < 64; ++d) o[d] = 0.0f;
        float l = 0.0f;
        for (int key = 0; key <= q; ++key) {
            const f16* Kr = kh + head + (size_t)key * HD;
            float s = 0.0f;
            for (int d = 0; d < 64; ++d) s = fmaf(qv[d], (float)Kr[pcol64(d)], s);
            const float p = __expf(s * 0.125f - mx);
            l += p;
            for (int d = 0; d < 64; ++d)
                o[d] = fmaf(p, (float)vt[head + (size_t)d * S + key], o[d]);
        }
        for (int d = 0; d < 64; ++d)
            y[fidx(b * S + q, h * 64 + d)] = (f16)(o[d] / l);
    }
#endif
}

// ---------------------------------------------------------------------------
// ws layout (32 MB total, unchanged):
//   [0,8M)   qh            -> after attn: wo frag f16 (2MB)
//   [8,16M)  kh
//   [16,24M) vt
//   [24,32M) wqkv frag f16 (6MB, dead after gemm_qkv) -> y frag (8MB)
// ---------------------------------------------------------------------------
extern "C" void kernel_launch(void* const* d_in, const int* in_sizes, int n_in,
                              void* d_out, int out_size, void* d_ws, size_t ws_size,
                              hipStream_t stream)
{
    f16* ws = (f16*)d_ws;
    const size_t SEG = (size_t)4 * 1024 * 1024;   // 4M f16 = 8 MB per region
    f16* qh   = ws;
    f16* kh   = ws + SEG;
    f16* vt   = ws + 2 * SEG;
    f16* wqkv = ws + 3 * SEG;   // 3M f16, dead after gemm_qkv
    f16* y    = ws + 3 * SEG;   // attn overwrites the wqkv region
    f16* wo   = ws;             // wo frag into the dead qh region (after attn)

    cvt_w<<<dim3(512, 3), 256, 0, stream>>>(
        (const float*)d_in[4], (const float*)d_in[6], (const float*)d_in[8], wqkv);
    gemm_qkv<<<dim3(64, 8, 3), 256, 0, stream>>>(
        (const float*)d_in[0], (const float*)d_in[1], (const float*)d_in[2],
        wqkv,
        (const float*)d_in[5], (const float*)d_in[7], (const float*)d_in[9],
        qh, kh, vt);
    // d_in[3] = causal tril mask, hardcoded
    attn_fwd<<<dim3(4 * NH * (S / 64)), 256, 0, stream>>>(qh, kh, vt, y);
    cvt_w<<<dim3(512, 1), 256, 0, stream>>>(
        (const float*)d_in[10], nullptr, nullptr, wo);
    gemm_out<<<dim3(64, 16), 256, 0, stream>>>(
        y, wo, (const float*)d_in[11], (float*)d_out);
}

// Round 6
// 253.473 us; speedup vs baseline: 1.1135x; 1.1135x over previous
//
#include <hip/hip_runtime.h>

// Round 15: all-DMA staging for BOTH GEMM operands (m97 parity).
// Diagnosis r10-r14: every variant with the fp32-A register-staging chain
// (global->VGPR->cvt->ds_write) lands 67-99 us; m97 (same geometry, both
// operands global_load_lds) does 3x better on this chip. The chain inserts
// compiler vmcnt waits + VALU cvt into every iter. Fix:
// - A (fp32 q/k/v) staged via global_load_lds DIRECTLY as fp32 (16KB/buf);
//   bank swizzle achieved by pre-swizzling the per-lane GLOBAL source column
//   (slot ^= row&7 within the 128B row; LDS dest linear = m173 pattern).
//   f32->f16 cvt moved to fragment-read time (off the staging path).
// - W f16 pre-swizzled by cvt_w (r13 layout, verified) + gll.
// - 2-buffer, plain __syncthreads drain (m97 structure), 128x128, BK=32,
//   4 waves, 64x64/wave, 3 blocks/CU (48KB LDS).
// - gemm_out: same all-f16 DMA core at 64x64 tiles, grid (64,16)=1024 blocks
//   -> 4 blk/CU (was 1 blk/CU since r13 — hidden occupancy hole).
// attn + cvt_w reverted to round-13 exact (passing).

using f16    = _Float16;
using f16x4  = __attribute__((ext_vector_type(4))) _Float16;
using f16x8  = __attribute__((ext_vector_type(8))) _Float16;
using f32x4  = __attribute__((ext_vector_type(4))) float;
using f32x16 = __attribute__((ext_vector_type(16))) float;

static constexpr int S = 1024, Dm = 1024, NH = 16, HD = 64;

#if __has_builtin(__builtin_amdgcn_mfma_f32_32x32x16_f16)
#define USE_G32 1
#define MFMA32(ACC, A_, B_) \
    (ACC) = __builtin_amdgcn_mfma_f32_32x32x16_f16((A_), (B_), (ACC), 0, 0, 0)
#else
#define USE_G32 0
#endif

#if __has_builtin(__builtin_amdgcn_mfma_f32_16x16x32_f16) && \
    __has_builtin(__builtin_amdgcn_mfma_f32_16x16x16f16)
#define USE_A16 1
#define MFMA16K32(ACC, A_, B_) \
    (ACC) = __builtin_amdgcn_mfma_f32_16x16x32_f16((A_), (B_), (ACC), 0, 0, 0)
#define MFMA16(ACC, A_, B_) \
    (ACC) = __builtin_amdgcn_mfma_f32_16x16x16f16((A_), (B_), (ACC), 0, 0, 0)
#else
#define USE_A16 0
#endif

#define LO4(v) __builtin_shufflevector((v), (v), 0, 1, 2, 3)
#define HI4(v) __builtin_shufflevector((v), (v), 4, 5, 6, 7)

__device__ __forceinline__ f16x4 cvt4(float4 a) {
    f16x4 r; r[0] = (f16)a.x; r[1] = (f16)a.y; r[2] = (f16)a.z; r[3] = (f16)a.w;
    return r;
}

// hd permutation for qh/kh (K=32 QK MFMA), verified round 10.
__device__ __forceinline__ int pcol64(int k) {
#if USE_A16
    return ((k >> 3) & 3) * 16 + ((k >> 5) << 3) + (k & 7);
#else
    return ((k >> 2) & 3) * 16 + ((k >> 4) << 2) + (k & 3);
#endif
}

// f16 bank swizzle for 32-f16 (64B) chunks (r13, verified): 16B slot (2b)
// ^= (row>>1)&3. Granule (row&1)*4 + slot^((row>>1)&3) distinct over 8 rows.
__device__ __forceinline__ int swz(int row, int col) {
    return (col & ~31) | ((((col >> 3) ^ (row >> 1)) & 3) << 3) | (col & 7);
}

// mode 0: [B,H,S,HD] f16 hd-permuted; 1: [B,H,HD,S] f16
__device__ __forceinline__ void store_out(void* out, int mode, int m, int n, float v) {
    const int b_ = m >> 10, s_ = m & 1023, h_ = n >> 6, hd_ = n & 63;
    const size_t idx = (mode == 0)
        ? (((size_t)(b_ * NH + h_) * S + s_) * HD + pcol64(hd_))
        : (((size_t)(b_ * NH + h_) * HD + hd_) * S + s_);
    ((f16*)out)[idx] = (f16)v;
}

#if __has_builtin(__builtin_amdgcn_global_load_lds)
#define HAS_GLL 1
#else
#define HAS_GLL 0
#endif

__device__ __forceinline__ void gll16(const void* g, void* l) {
#if HAS_GLL
    __builtin_amdgcn_global_load_lds(
        (const __attribute__((address_space(1))) void*)g,
        (__attribute__((address_space(3))) void*)l, 16, 0, 0);
#else
    *(uint4*)l = *(const uint4*)g;   // sync fallback; drained by barrier
#endif
}

// ---------------------------------------------------------------------------
// fp32 W -> f16, swz layout (r13 exact). grid (1024, nmat); one float4/thread.
// ---------------------------------------------------------------------------
__global__ __launch_bounds__(256)
void cvt_w(const float* __restrict__ s0, const float* __restrict__ s1,
           const float* __restrict__ s2, f16* __restrict__ dst)
{
    const int z = blockIdx.y;
    const float* src = (z == 0) ? s0 : (z == 1) ? s1 : s2;
    const int e = blockIdx.x * 256 + threadIdx.x;
    const int n = e >> 8;
    const int k = (e & 255) * 4;
    const float4 v = *(const float4*)(src + (size_t)n * Dm + k);
    *(f16x4*)(dst + (size_t)z * Dm * Dm + (size_t)n * Dm + swz(n, k)) = cvt4(v);
}

// ---------------------------------------------------------------------------
// gemm_qkv: out = relu(A @ W^T + b). 128x128 tile, BK=32, 2-buffer, 4 waves,
// 64x64/wave (2x2 32x32 acc), 8 MFMA/iter/wave. Staging = pure DMA:
//   A fp32: 4 gll/thread/iter, source col pre-swizzled slot^=(row&7)
//           (within-row permutation -> coalesced), LDS dest linear.
//   W f16 : 2 gll/thread/iter (global pre-swizzled by cvt_w).
// Frag reads: A = 2x b128 fp32 + 8 cvt (both slots conflict-free: rows r..r+7
// cover 8 distinct 16B granules); W = 1x b128 (r13 swz).
// 32x32x16 maps (HW-verified r10-13): A lane l: A[m=l&31][k=8*(l>>5)+j];
// C/D reg i: row=8*(i>>2)+4*(l>>5)+(i&3), col=l&31.
// ---------------------------------------------------------------------------
__global__ __launch_bounds__(256, 3)
void gemm_qkv(const float* __restrict__ q, const float* __restrict__ k,
              const float* __restrict__ v, const f16* __restrict__ wqkv,
              const float* __restrict__ bq, const float* __restrict__ bk,
              const float* __restrict__ bv,
              f16* __restrict__ qh, f16* __restrict__ kh, f16* __restrict__ vt)
{
    const int z = blockIdx.z;
    const float* A = (z == 0) ? q : (z == 1) ? k : v;
    const float* bias = (z == 0) ? bq : (z == 1) ? bk : bv;
    f16* out = (z == 0) ? qh : (z == 1) ? kh : vt;
    const int mode = (z == 2) ? 1 : 0;
    const f16* Wf = wqkv + (size_t)z * Dm * Dm;

    const int tid = threadIdx.x;
    const int bm = blockIdx.x, bn = blockIdx.y;   // (32, 8)
#if USE_G32
    __shared__ alignas(16) float As[2][128][32];  // 2 x 16 KB
    __shared__ alignas(16) f16   Ws[2][128][32];  // 2 x  8 KB  (48 KB -> 3/CU)

    const int lane = tid & 63, wave = tid >> 6;
    const int l31 = lane & 31, kh2 = lane >> 5;
    const int wm = wave & 1, wn = wave >> 1;

    // A DMA: chunk ch = rows [ch*32, +32); LDS linear dest = ch*4KB + tid*16.
    // Source col pre-swizzled: LDS[row][slotD] <- A[row][slotD ^ (row&7)].
    const int arow = tid >> 3;                   // 0..31 (row within chunk)
    const int aslotD = tid & 7;
    const int aslotS = aslotD ^ (arow & 7);      // ch*32 ≡ 0 (mod 8) -> const
    const float* Asrc0 = A + (size_t)(bm * 128 + arow) * Dm + aslotS * 4;
    // W DMA: chunk ch = rows [ch*64, +64); dest = ch*4KB + tid*16. Linear
    // (global already swz'd by cvt_w).
    const int wrow = tid >> 2, wcol = (tid & 3) * 8;
    const f16* Wsrc0 = Wf + (size_t)(bn * 128 + wrow) * Dm + wcol;

    auto dma = [&](int k0, int buf) {
#pragma unroll
        for (int ch = 0; ch < 4; ++ch)
            gll16(Asrc0 + (size_t)ch * 32 * Dm + k0,
                  &As[buf][ch * 32 + arow][aslotD * 4]);
        gll16(Wsrc0 + k0,                    &Ws[buf][wrow][wcol]);
        gll16(Wsrc0 + (size_t)64 * Dm + k0,  &Ws[buf][64 + wrow][wcol]);
    };

    auto afrag = [&](int buf, int r, int s) -> f16x8 {
        const int p = s * 4 + kh2 * 2, r7 = r & 7;
        const f32x4 lo = *(const f32x4*)&As[buf][r][(p ^ r7) * 4];
        const f32x4 hi = *(const f32x4*)&As[buf][r][((p + 1) ^ r7) * 4];
        f16x8 f;
        f[0] = (f16)lo[0]; f[1] = (f16)lo[1]; f[2] = (f16)lo[2]; f[3] = (f16)lo[3];
        f[4] = (f16)hi[0]; f[5] = (f16)hi[1]; f[6] = (f16)hi[2]; f[7] = (f16)hi[3];
        return f;
    };
    auto wfrag = [&](int buf, int r, int s) -> f16x8 {
        const int sl = s * 2 + kh2;
        return *(const f16x8*)&Ws[buf][r][((sl ^ (r >> 1)) & 3) * 8];
    };

    f32x16 acc[2][2] = {};
    auto kslice = [&](int buf, int s) {
        const f16x8 af0 = afrag(buf, wm * 64 + l31, s);
        const f16x8 af1 = afrag(buf, wm * 64 + 32 + l31, s);
        const f16x8 bf0 = wfrag(buf, wn * 64 + l31, s);
        const f16x8 bf1 = wfrag(buf, wn * 64 + 32 + l31, s);
        MFMA32(acc[0][0], af0, bf0);
        MFMA32(acc[0][1], af0, bf1);
        MFMA32(acc[1][0], af1, bf0);
        MFMA32(acc[1][1], af1, bf1);
    };

    constexpr int NIT = Dm / 32;   // 32
    dma(0, 0);
    for (int t = 0; t < NIT; ++t) {
        const int cur = t & 1;
        __syncthreads();                         // drains dma(t)
        if (t + 1 < NIT) dma((t + 1) * 32, cur ^ 1);
        kslice(cur, 0);
        kslice(cur, 1);
    }

    // epilogue (C/D map verified r10-13)
#pragma unroll
    for (int g2 = 0; g2 < 2; ++g2) {
        const int col = bn * 128 + wn * 64 + g2 * 32 + l31;
        const float bb = bias[col];
#pragma unroll
        for (int g = 0; g < 2; ++g)
#pragma unroll
            for (int blk = 0; blk < 4; ++blk) {
                const int row0 = bm * 128 + wm * 64 + g * 32 + 8 * blk + 4 * kh2;
                if (mode == 1) {   // [B,H,HD,S]: 4 consecutive s -> packed b64
                    const int b_ = row0 >> 10, s_ = row0 & 1023;
                    const int h_ = col >> 6, hd_ = col & 63;
                    f16x4 vv;
#pragma unroll
                    for (int r = 0; r < 4; ++r)
                        vv[r] = (f16)fmaxf(acc[g][g2][blk * 4 + r] + bb, 0.0f);
                    *(f16x4*)&out[((size_t)(b_ * NH + h_) * HD + hd_) * S + s_] = vv;
                } else {
#pragma unroll
                    for (int r = 0; r < 4; ++r)
                        store_out(out, mode, row0 + r, col,
                                  fmaxf(acc[g][g2][blk * 4 + r] + bb, 0.0f));
                }
            }
    }
#else
    for (int i = tid; i < 128 * 128; i += 256) {
        const int m = bm * 128 + (i >> 7);
        const int n = bn * 128 + (i & 127);
        float acc = 0.0f;
        for (int k2 = 0; k2 < Dm; ++k2)
            acc = fmaf(A[(size_t)m * Dm + k2], (float)Wf[(size_t)n * Dm + swz(n, k2)], acc);
        store_out(out, mode, m, n, fmaxf(acc + bias[n], 0.0f));
    }
#endif
}

// ---------------------------------------------------------------------------
// gemm_out: out = relu(y @ Wo^T + b), fp32 out. Both operands f16 swz (y from
// attn, wo from cvt_w), all-DMA. 64x64 tile, grid (64,16)=1024 -> 4 blk/CU,
// 4 waves (2x2), 32x32/wave, 2 MFMA/iter/wave. LDS 2x(4+4)KB = 16 KB.
// ---------------------------------------------------------------------------
__global__ __launch_bounds__(256, 4)
void gemm_out(const f16* __restrict__ y, const f16* __restrict__ wo,
              const float* __restrict__ bo, float* __restrict__ out)
{
    const int tid = threadIdx.x;
    const int bm = blockIdx.x, bn = blockIdx.y;   // (64, 16)
#if USE_G32
    __shared__ alignas(16) f16 As[2][64][32];
    __shared__ alignas(16) f16 Ws[2][64][32];

    const int lane = tid & 63, wave = tid >> 6;
    const int l31 = lane & 31, kh2 = lane >> 5;
    const int wm = wave & 1, wn = wave >> 1;

    const int drow = tid >> 2, dcol = (tid & 3) * 8;
    const f16* Asrc = y  + (size_t)(bm * 64 + drow) * Dm + dcol;
    const f16* Wsrc = wo + (size_t)(bn * 64 + drow) * Dm + dcol;

    auto dma = [&](int k0, int buf) {
        gll16(Asrc + k0, &As[buf][drow][dcol]);
        gll16(Wsrc + k0, &Ws[buf][drow][dcol]);
    };
    auto frag = [&](const f16 (&L)[64][32], int r, int s) -> f16x8 {
        const int sl = s * 2 + kh2;
        return *(const f16x8*)&L[r][((sl ^ (r >> 1)) & 3) * 8];
    };

    f32x16 acc = {};
    constexpr int NIT = Dm / 32;   // 32
    dma(0, 0);
    for (int t = 0; t < NIT; ++t) {
        const int cur = t & 1;
        __syncthreads();
        if (t + 1 < NIT) dma((t + 1) * 32, cur ^ 1);
#pragma unroll
        for (int s = 0; s < 2; ++s) {
            const f16x8 af = frag(As[cur], wm * 32 + l31, s);
            const f16x8 bf = frag(Ws[cur], wn * 32 + l31, s);
            MFMA32(acc, af, bf);
        }
    }

    const int col = bn * 64 + wn * 32 + l31;
    const float bb = bo[col];
#pragma unroll
    for (int blk = 0; blk < 4; ++blk) {
        const int row0 = bm * 64 + wm * 32 + 8 * blk + 4 * kh2;
#pragma unroll
        for (int r = 0; r < 4; ++r)
            out[(size_t)(row0 + r) * Dm + col] = fmaxf(acc[blk * 4 + r] + bb, 0.0f);
    }
#else
    for (int i = tid; i < 64 * 64; i += 256) {
        const int m = bm * 64 + (i >> 6);
        const int n = bn * 64 + (i & 63);
        float acc = 0.0f;
        for (int k2 = 0; k2 < Dm; ++k2)
            acc = fmaf((float)y[(size_t)m * Dm + swz(m, k2)],
                       (float)wo[(size_t)n * Dm + swz(n, k2)], acc);
        out[(size_t)m * Dm + n] = fmaxf(acc + bo[n], 0.0f);
    }
#endif
}

// ---------------------------------------------------------------------------
// Flash attention — round-13 exact (passing); y stored swz for gemm_out DMA.
// ---------------------------------------------------------------------------
__global__ __launch_bounds__(256)
void attn_fwd(const f16* __restrict__ qh, const f16* __restrict__ kh,
              const f16* __restrict__ vt, f16* __restrict__ y)
{
    const int bz = blockIdx.x;       // B*H*(S/64) = 1024
    const int qt = bz & 15;
    const int h  = (bz >> 4) & 15;
    const int b  = bz >> 8;
    const size_t head = (size_t)(b * NH + h) * S * HD;

#if USE_A16
    __shared__ alignas(16) f16 Ks[2][64][72];
    __shared__ alignas(16) f16 Vs[2][64][72];

    const int tid  = threadIdx.x;
    const int wave = tid >> 6;
    const int lane = tid & 63;
    const int l15  = lane & 15;
    const int quad = lane >> 4;
    const int sr   = tid >> 2;
    const int sc   = (tid & 3) * 16;

    const f16* Qrow = qh + head + (size_t)(qt * 64 + wave * 16 + l15) * HD;
    const f16* Kp   = kh + head;
    const f16* Vp   = vt + head;

    f16x8 aq[2];
    {
        const uint4 q0 = *(const uint4*)(Qrow + quad * 16);
        const uint4 q1 = *(const uint4*)(Qrow + quad * 16 + 8);
        aq[0] = *(f16x8*)&q0;
        aq[1] = *(f16x8*)&q1;
    }

    const int qg = qt * 64 + wave * 16 + l15;
    float m_i = -1e30f, l_i = 0.0f;
    f32x4 acc_o[4] = {};

    uint4 pk[2], pv[2];
    auto pref = [&](int kt) {
        const f16* Kr = Kp + (size_t)(kt * 64 + sr) * HD + sc;
        pk[0] = *(const uint4*)Kr;
        pk[1] = *(const uint4*)(Kr + 8);
        const f16* Vr = Vp + (size_t)sr * S + kt * 64 + sc;
        pv[0] = *(const uint4*)Vr;
        pv[1] = *(const uint4*)(Vr + 8);
    };

    pref(0);
    for (int kt = 0; kt <= qt; ++kt) {
        const int cur = kt & 1;
        *(uint4*)&Ks[cur][sr][sc]     = pk[0];
        *(uint4*)&Ks[cur][sr][sc + 8] = pk[1];
        {
            const int sb = (sc >> 4) * 4;
            *(f16x4*)&Vs[cur][sr][0 * 16 + sb] = *(f16x4*)((f16*)&pv[0]);
            *(f16x4*)&Vs[cur][sr][1 * 16 + sb] = *(f16x4*)((f16*)&pv[0] + 4);
            *(f16x4*)&Vs[cur][sr][2 * 16 + sb] = *(f16x4*)((f16*)&pv[1]);
            *(f16x4*)&Vs[cur][sr][3 * 16 + sb] = *(f16x4*)((f16*)&pv[1] + 4);
        }
        __syncthreads();
        if (kt < qt) pref(kt + 1);

        f32x4 accs[4] = {};
#pragma unroll
        for (int t = 0; t < 4; ++t) {
            const f16x8 k8a = *(const f16x8*)&Ks[cur][t * 16 + l15][quad * 16];
            const f16x8 k8b = *(const f16x8*)&Ks[cur][t * 16 + l15][quad * 16 + 8];
            MFMA16K32(accs[t], k8a, aq[0]);
            MFMA16K32(accs[t], k8b, aq[1]);
        }

        const int key0 = kt * 64 + quad * 4;
#pragma unroll
        for (int t = 0; t < 4; ++t)
#pragma unroll
            for (int r = 0; r < 4; ++r) {
                float sv = accs[t][r] * 0.125f;
                if (key0 + t * 16 + r > qg) sv = -1e9f;
                accs[t][r] = sv;
            }

        float mx = accs[0][0];
#pragma unroll
        for (int t = 0; t < 4; ++t)
#pragma unroll
            for (int r = 0; r < 4; ++r) mx = fmaxf(mx, accs[t][r]);
        mx = fmaxf(mx, __shfl_xor(mx, 16, 64));
        mx = fmaxf(mx, __shfl_xor(mx, 32, 64));
        const float mnew = fmaxf(m_i, mx);
        float sm = 0.0f;
#pragma unroll
        for (int t = 0; t < 4; ++t)
#pragma unroll
            for (int r = 0; r < 4; ++r) {
                const float e = __expf(accs[t][r] - mnew);
                accs[t][r] = e;
                sm += e;
            }
        sm += __shfl_xor(sm, 16, 64);
        sm += __shfl_xor(sm, 32, 64);
        const float alpha = __expf(m_i - mnew);
        l_i = l_i * alpha + sm;
        m_i = mnew;

        f16x4 ap[4];
#pragma unroll
        for (int c = 0; c < 4; ++c) {
            f16x4 v;
#pragma unroll
            for (int j = 0; j < 4; ++j) v[j] = (f16)accs[c][j];
            ap[c] = v;
        }

        float ar[4];
#pragma unroll
        for (int r = 0; r < 4; ++r) ar[r] = __shfl(alpha, quad * 4 + r, 64);
#pragma unroll
        for (int t2 = 0; t2 < 4; ++t2)
#pragma unroll
            for (int r = 0; r < 4; ++r) acc_o[t2][r] *= ar[r];
#pragma unroll
        for (int t2 = 0; t2 < 4; ++t2) {
            const f16x8 v8a = *(const f16x8*)&Vs[cur][t2 * 16 + l15][quad * 16];
            const f16x8 v8b = *(const f16x8*)&Vs[cur][t2 * 16 + l15][quad * 16 + 8];
            MFMA16(acc_o[t2], ap[0], LO4(v8a));
            MFMA16(acc_o[t2], ap[1], HI4(v8a));
            MFMA16(acc_o[t2], ap[2], LO4(v8b));
            MFMA16(acc_o[t2], ap[3], HI4(v8b));
        }
    }

    float lr[4];
#pragma unroll
    for (int r = 0; r < 4; ++r) lr[r] = __shfl(l_i, quad * 4 + r, 64);
#pragma unroll
    for (int t2 = 0; t2 < 4; ++t2)
#pragma unroll
        for (int r = 0; r < 4; ++r) {
            const int srow = qt * 64 + wave * 16 + quad * 4 + r;
            const int dcol = h * 64 + t2 * 16 + l15;
            y[((size_t)b * S + srow) * Dm + swz(srow, dcol)] =
                (f16)(acc_o[t2][r] / lr[r]);
        }
#else
    const int tid = threadIdx.x;
    if (tid < 64) {
        const int q = qt * 64 + tid;
        const f16* Qr = qh + head + (size_t)q * HD;
        float qv[64];
        for (int d = 0; d < 64; ++d) qv[d] = (float)Qr[pcol64(d)];
        float mx = -1e30f;
        for (int key = 0; key <= q; ++key) {
            const f16* Kr = kh + head + (size_t)key * HD;
            float s = 0.0f;
            for (int d = 0; d < 64; ++d) s = fmaf(qv[d], (float)Kr[pcol64(d)], s);
            mx = fmaxf(mx, s * 0.125f);
        }
        float o[64];
        for (int d = 0; d < 64; ++d) o[d] = 0.0f;
        float l = 0.0f;
        for (int key = 0; key <= q; ++key) {
            const f16* Kr = kh + head + (size_t)key * HD;
            float s = 0.0f;
            for (int d = 0; d < 64; ++d) s = fmaf(qv[d], (float)Kr[pcol64(d)], s);
            const float p = __expf(s * 0.125f - mx);
            l += p;
            for (int d = 0; d < 64; ++d)
                o[d] = fmaf(p, (float)vt[head + (size_t)d * S + key], o[d]);
        }
        for (int d = 0; d < 64; ++d)
            y[((size_t)b * S + q) * Dm + swz(q, h * 64 + d)] = (f16)(o[d] / l);
    }
#endif
}

// ---------------------------------------------------------------------------
// ws layout (32 MB total, unchanged):
//   [0,8M)   qh            -> after attn: Wo f16 (2MB)
//   [8,16M)  kh
//   [16,24M) vt
//   [24,32M) Wq/Wk/Wv f16 (6MB, dead after gemm_qkv) -> y (8MB, from attn)
// ---------------------------------------------------------------------------
extern "C" void kernel_launch(void* const* d_in, const int* in_sizes, int n_in,
                              void* d_out, int out_size, void* d_ws, size_t ws_size,
                              hipStream_t stream)
{
    f16* ws = (f16*)d_ws;
    const size_t SEG = (size_t)4 * 1024 * 1024;   // 4M f16 = 8 MB per region
    f16* qh   = ws;
    f16* kh   = ws + SEG;
    f16* vt   = ws + 2 * SEG;
    f16* wqkv = ws + 3 * SEG;   // 3M f16, dead after gemm_qkv
    f16* y    = ws + 3 * SEG;   // attn overwrites the wqkv region
    f16* wo   = ws;             // Wo f16 into the dead qh region (after attn)

    cvt_w<<<dim3(1024, 3), 256, 0, stream>>>(
        (const float*)d_in[4], (const float*)d_in[6], (const float*)d_in[8], wqkv);
    gemm_qkv<<<dim3(32, 8, 3), 256, 0, stream>>>(
        (const float*)d_in[0], (const float*)d_in[1], (const float*)d_in[2],
        wqkv,
        (const float*)d_in[5], (const float*)d_in[7], (const float*)d_in[9],
        qh, kh, vt);
    // d_in[3] = causal tril mask, hardcoded
    attn_fwd<<<dim3(4 * NH * (S / 64)), 256, 0, stream>>>(qh, kh, vt, y);
    cvt_w<<<dim3(1024, 1), 256, 0, stream>>>(
        (const float*)d_in[10], nullptr, nullptr, wo);
    gemm_out<<<dim3(64, 16), 256, 0, stream>>>(
        y, wo, (const float*)d_in[11], (float*)d_out);
}

// Round 7
// 251.184 us; speedup vs baseline: 1.1237x; 1.0091x over previous
//
#include <hip/hip_runtime.h>

// Round 16: merge proven-best pieces; cut a launch.
// - Counter decode: SQ_LDS_BANK_CONFLICT == 4 cy per ds_read_b128 exactly
//   (r12 3.1M, r13/r15 4.7M all reproduce) -> LDS is at its structural floor,
//   never conflicted. Dead lever.
// - gemm_qkv: r13 wave geometry (512 thr, 8 waves, 32x64/wave — best measured,
//   67 us) + r15 staging (all-DMA: A fp32 via global_load_lds with source-col
//   pre-swizzle, frag-time cvt — removes the stage VALU chain). 2-buf drain,
//   48 KB LDS -> 3 blk/CU = 24 waves/CU.
// - gemm_out: wo staged as fp32 DMA (frag-time cvt, r15's verified A-path) ->
//   the second cvt_w launch + its gap are DELETED. 64x64 tile, 24 KB LDS ->
//   6 blk/CU. y f16 swz DMA (unchanged).
// - attn + cvt_w(wqkv) byte-identical to r15 (passing).

using f16    = _Float16;
using f16x4  = __attribute__((ext_vector_type(4))) _Float16;
using f16x8  = __attribute__((ext_vector_type(8))) _Float16;
using f32x4  = __attribute__((ext_vector_type(4))) float;
using f32x16 = __attribute__((ext_vector_type(16))) float;

static constexpr int S = 1024, Dm = 1024, NH = 16, HD = 64;

#if __has_builtin(__builtin_amdgcn_mfma_f32_32x32x16_f16)
#define USE_G32 1
#define MFMA32(ACC, A_, B_) \
    (ACC) = __builtin_amdgcn_mfma_f32_32x32x16_f16((A_), (B_), (ACC), 0, 0, 0)
#else
#define USE_G32 0
#endif

#if __has_builtin(__builtin_amdgcn_mfma_f32_16x16x32_f16) && \
    __has_builtin(__builtin_amdgcn_mfma_f32_16x16x16f16)
#define USE_A16 1
#define MFMA16K32(ACC, A_, B_) \
    (ACC) = __builtin_amdgcn_mfma_f32_16x16x32_f16((A_), (B_), (ACC), 0, 0, 0)
#define MFMA16(ACC, A_, B_) \
    (ACC) = __builtin_amdgcn_mfma_f32_16x16x16f16((A_), (B_), (ACC), 0, 0, 0)
#else
#define USE_A16 0
#endif

#define LO4(v) __builtin_shufflevector((v), (v), 0, 1, 2, 3)
#define HI4(v) __builtin_shufflevector((v), (v), 4, 5, 6, 7)

__device__ __forceinline__ f16x4 cvt4(float4 a) {
    f16x4 r; r[0] = (f16)a.x; r[1] = (f16)a.y; r[2] = (f16)a.z; r[3] = (f16)a.w;
    return r;
}

// hd permutation for qh/kh (K=32 QK MFMA), verified round 10.
__device__ __forceinline__ int pcol64(int k) {
#if USE_A16
    return ((k >> 3) & 3) * 16 + ((k >> 5) << 3) + (k & 7);
#else
    return ((k >> 2) & 3) * 16 + ((k >> 4) << 2) + (k & 3);
#endif
}

// f16 bank swizzle for 32-f16 (64B) chunks (verified r13/r15): 16B slot (2b)
// ^= (row>>1)&3.
__device__ __forceinline__ int swz(int row, int col) {
    return (col & ~31) | ((((col >> 3) ^ (row >> 1)) & 3) << 3) | (col & 7);
}

// mode 0: [B,H,S,HD] f16 hd-permuted; 1: [B,H,HD,S] f16
__device__ __forceinline__ void store_out(void* out, int mode, int m, int n, float v) {
    const int b_ = m >> 10, s_ = m & 1023, h_ = n >> 6, hd_ = n & 63;
    const size_t idx = (mode == 0)
        ? (((size_t)(b_ * NH + h_) * S + s_) * HD + pcol64(hd_))
        : (((size_t)(b_ * NH + h_) * HD + hd_) * S + s_);
    ((f16*)out)[idx] = (f16)v;
}

#if __has_builtin(__builtin_amdgcn_global_load_lds)
#define HAS_GLL 1
#else
#define HAS_GLL 0
#endif

__device__ __forceinline__ void gll16(const void* g, void* l) {
#if HAS_GLL
    __builtin_amdgcn_global_load_lds(
        (const __attribute__((address_space(1))) void*)g,
        (__attribute__((address_space(3))) void*)l, 16, 0, 0);
#else
    *(uint4*)l = *(const uint4*)g;   // sync fallback; drained by barrier
#endif
}

// ---------------------------------------------------------------------------
// fp32 W -> f16, swz layout (verified). grid (1024, 3); one float4/thread.
// ---------------------------------------------------------------------------
__global__ __launch_bounds__(256)
void cvt_w(const float* __restrict__ s0, const float* __restrict__ s1,
           const float* __restrict__ s2, f16* __restrict__ dst)
{
    const int z = blockIdx.y;
    const float* src = (z == 0) ? s0 : (z == 1) ? s1 : s2;
    const int e = blockIdx.x * 256 + threadIdx.x;
    const int n = e >> 8;
    const int k = (e & 255) * 4;
    const float4 v = *(const float4*)(src + (size_t)n * Dm + k);
    *(f16x4*)(dst + (size_t)z * Dm * Dm + (size_t)n * Dm + swz(n, k)) = cvt4(v);
}

// ---------------------------------------------------------------------------
// gemm_qkv: out = relu(A @ W^T + b). 128x128 tile, BK=32, 2-buffer drain,
// 512 threads = 8 waves (4m x 2n), 32x64/wave, 4 MFMA/iter/wave. All-DMA:
//   A fp32: 2 gll/thread/iter; source col pre-swizzled (16B slot ^= row&7
//   within the 128B k-chunk; coalesced within-row permutation); LDS linear
//   (byte = ch*8KB + tid*16). f32->f16 cvt at frag-read.
//   W f16 : 1 gll/thread/iter (global pre-swizzled by cvt_w; byte = tid*16).
// Frag maps HW-verified r10-r15. LDS 48 KB -> 3 blk/CU (24 waves).
// ---------------------------------------------------------------------------
__global__ __launch_bounds__(512, 6)
void gemm_qkv(const float* __restrict__ q, const float* __restrict__ k,
              const float* __restrict__ v, const f16* __restrict__ wqkv,
              const float* __restrict__ bq, const float* __restrict__ bk,
              const float* __restrict__ bv,
              f16* __restrict__ qh, f16* __restrict__ kh, f16* __restrict__ vt)
{
    const int z = blockIdx.z;
    const float* A = (z == 0) ? q : (z == 1) ? k : v;
    const float* bias = (z == 0) ? bq : (z == 1) ? bk : bv;
    f16* out = (z == 0) ? qh : (z == 1) ? kh : vt;
    const int mode = (z == 2) ? 1 : 0;
    const f16* Wf = wqkv + (size_t)z * Dm * Dm;

    const int tid = threadIdx.x;
    const int bm = blockIdx.x, bn = blockIdx.y;   // (32, 8)
#if USE_G32
    __shared__ alignas(16) float As[2][128][32];  // 2 x 16 KB
    __shared__ alignas(16) f16   Ws[2][128][32];  // 2 x  8 KB (48 KB total)

    const int lane = tid & 63, wave = tid >> 6;
    const int l31 = lane & 31, kh2 = lane >> 5;
    const int wm = wave & 3, wn = wave >> 2;      // 4 row-groups x 2 col-groups

    // A DMA: ch in {0,1} covers rows [ch*64, +64); LDS byte = ch*8KB + tid*16.
    const int arow = tid >> 3;                    // 0..63
    const int aslotD = tid & 7;
    const int aslotS = aslotD ^ (arow & 7);       // 64 == 0 mod 8 -> ch-invariant
    const float* Asrc0 = A + (size_t)(bm * 128 + arow) * Dm + aslotS * 4;
    // W DMA: full 8KB buffer in one gll; byte = tid*16.
    const int wrow = tid >> 2, wcol = (tid & 3) * 8;
    const f16* Wsrc0 = Wf + (size_t)(bn * 128 + wrow) * Dm + wcol;

    auto dma = [&](int k0, int buf) {
        gll16(Asrc0 + k0,                      &As[buf][arow][aslotD * 4]);
        gll16(Asrc0 + (size_t)64 * Dm + k0,    &As[buf][64 + arow][aslotD * 4]);
        gll16(Wsrc0 + k0,                      &Ws[buf][wrow][wcol]);
    };

    auto afrag = [&](int buf, int r, int s) -> f16x8 {
        const int p = s * 4 + kh2 * 2, r7 = r & 7;
        const f32x4 lo = *(const f32x4*)&As[buf][r][(p ^ r7) * 4];
        const f32x4 hi = *(const f32x4*)&As[buf][r][((p + 1) ^ r7) * 4];
        f16x8 f;
        f[0] = (f16)lo[0]; f[1] = (f16)lo[1]; f[2] = (f16)lo[2]; f[3] = (f16)lo[3];
        f[4] = (f16)hi[0]; f[5] = (f16)hi[1]; f[6] = (f16)hi[2]; f[7] = (f16)hi[3];
        return f;
    };
    auto wfrag = [&](int buf, int r, int s) -> f16x8 {
        const int sl = s * 2 + kh2;
        return *(const f16x8*)&Ws[buf][r][((sl ^ (r >> 1)) & 3) * 8];
    };

    f32x16 acc[2] = {};
    auto kslice = [&](int buf, int s) {
        const f16x8 af  = afrag(buf, wm * 32 + l31, s);
        const f16x8 bf0 = wfrag(buf, wn * 64 + l31, s);
        const f16x8 bf1 = wfrag(buf, wn * 64 + 32 + l31, s);
        MFMA32(acc[0], af, bf0);
        MFMA32(acc[1], af, bf1);
    };

    constexpr int NIT = Dm / 32;   // 32
    dma(0, 0);
    for (int t = 0; t < NIT; ++t) {
        const int cur = t & 1;
        __syncthreads();                          // drains dma(t)
        if (t + 1 < NIT) dma((t + 1) * 32, cur ^ 1);
        kslice(cur, 0);
        kslice(cur, 1);
    }

    // epilogue (C/D map verified; r13 8-wave layout, passing)
#pragma unroll
    for (int j = 0; j < 2; ++j) {
        const int col = bn * 128 + wn * 64 + j * 32 + l31;
        const float bb = bias[col];
#pragma unroll
        for (int blk = 0; blk < 4; ++blk) {
            const int row0 = bm * 128 + wm * 32 + 8 * blk + 4 * kh2;
            if (mode == 1) {   // [B,H,HD,S]: 4 consecutive s -> packed b64
                const int b_ = row0 >> 10, s_ = row0 & 1023;
                const int h_ = col >> 6, hd_ = col & 63;
                f16x4 vv;
#pragma unroll
                for (int r = 0; r < 4; ++r)
                    vv[r] = (f16)fmaxf(acc[j][blk * 4 + r] + bb, 0.0f);
                *(f16x4*)&out[((size_t)(b_ * NH + h_) * HD + hd_) * S + s_] = vv;
            } else {
#pragma unroll
                for (int r = 0; r < 4; ++r)
                    store_out(out, mode, row0 + r, col,
                              fmaxf(acc[j][blk * 4 + r] + bb, 0.0f));
            }
        }
    }
#else
    for (int i = tid; i < 128 * 128; i += 512) {
        const int m = bm * 128 + (i >> 7);
        const int n = bn * 128 + (i & 127);
        float acc = 0.0f;
        for (int k2 = 0; k2 < Dm; ++k2)
            acc = fmaf(A[(size_t)m * Dm + k2], (float)Wf[(size_t)n * Dm + swz(n, k2)], acc);
        store_out(out, mode, m, n, fmaxf(acc + bias[n], 0.0f));
    }
#endif
}

// ---------------------------------------------------------------------------
// gemm_out: out = relu(y @ Wo^T + b), fp32 out. y f16 swz (from attn) DMA;
// wo fp32 DMA with source-col pre-swizzle + frag-time cvt (NO cvt kernel).
// 64x64 tile, grid (64,16)=1024 blocks, 4 waves (2x2), 32x32/wave.
// LDS 2x(4+8)KB = 24 KB -> 6 blk/CU = 24 waves.
// ---------------------------------------------------------------------------
__global__ __launch_bounds__(256, 6)
void gemm_out(const f16* __restrict__ y, const float* __restrict__ wo,
              const float* __restrict__ bo, float* __restrict__ out)
{
    const int tid = threadIdx.x;
    const int bm = blockIdx.x, bn = blockIdx.y;   // (64, 16)
#if USE_G32
    __shared__ alignas(16) f16   As[2][64][32];   // 2 x 4 KB
    __shared__ alignas(16) float Wsf[2][64][32];  // 2 x 8 KB

    const int lane = tid & 63, wave = tid >> 6;
    const int l31 = lane & 31, kh2 = lane >> 5;
    const int wm = wave & 1, wn = wave >> 1;

    // y DMA: byte = tid*16, linear (global pre-swizzled by attn).
    const int drow = tid >> 2, dcol = (tid & 3) * 8;
    const f16* Asrc = y + (size_t)(bm * 64 + drow) * Dm + dcol;
    // wo fp32 DMA: ch in {0,1} covers rows [ch*32,+32); byte = ch*4KB + tid*16;
    // source 16B-slot pre-swizzled ^ (row&7).
    const int wrow = tid >> 3;                    // 0..31
    const int wslotD = tid & 7;
    const int wslotS = wslotD ^ (wrow & 7);
    const float* Wsrc0 = wo + (size_t)(bn * 64 + wrow) * Dm + wslotS * 4;

    auto dma = [&](int k0, int buf) {
        gll16(Asrc + k0, &As[buf][drow][dcol]);
        gll16(Wsrc0 + k0,                   &Wsf[buf][wrow][wslotD * 4]);
        gll16(Wsrc0 + (size_t)32 * Dm + k0, &Wsf[buf][32 + wrow][wslotD * 4]);
    };
    auto yfrag = [&](int buf, int r, int s) -> f16x8 {
        const int sl = s * 2 + kh2;
        return *(const f16x8*)&As[buf][r][((sl ^ (r >> 1)) & 3) * 8];
    };
    auto wfrag32 = [&](int buf, int r, int s) -> f16x8 {
        const int p = s * 4 + kh2 * 2, r7 = r & 7;
        const f32x4 lo = *(const f32x4*)&Wsf[buf][r][(p ^ r7) * 4];
        const f32x4 hi = *(const f32x4*)&Wsf[buf][r][((p + 1) ^ r7) * 4];
        f16x8 f;
        f[0] = (f16)lo[0]; f[1] = (f16)lo[1]; f[2] = (f16)lo[2]; f[3] = (f16)lo[3];
        f[4] = (f16)hi[0]; f[5] = (f16)hi[1]; f[6] = (f16)hi[2]; f[7] = (f16)hi[3];
        return f;
    };

    f32x16 acc = {};
    constexpr int NIT = Dm / 32;   // 32
    dma(0, 0);
    for (int t = 0; t < NIT; ++t) {
        const int cur = t & 1;
        __syncthreads();
        if (t + 1 < NIT) dma((t + 1) * 32, cur ^ 1);
#pragma unroll
        for (int s = 0; s < 2; ++s) {
            const f16x8 af = yfrag(cur, wm * 32 + l31, s);
            const f16x8 bf = wfrag32(cur, wn * 32 + l31, s);
            MFMA32(acc, af, bf);
        }
    }

    const int col = bn * 64 + wn * 32 + l31;
    const float bb = bo[col];
#pragma unroll
    for (int blk = 0; blk < 4; ++blk) {
        const int row0 = bm * 64 + wm * 32 + 8 * blk + 4 * kh2;
#pragma unroll
        for (int r = 0; r < 4; ++r)
            out[(size_t)(row0 + r) * Dm + col] = fmaxf(acc[blk * 4 + r] + bb, 0.0f);
    }
#else
    for (int i = tid; i < 64 * 64; i += 256) {
        const int m = bm * 64 + (i >> 6);
        const int n = bn * 64 + (i & 63);
        float acc = 0.0f;
        for (int k2 = 0; k2 < Dm; ++k2)
            acc = fmaf((float)y[(size_t)m * Dm + swz(m, k2)],
                       wo[(size_t)n * Dm + k2], acc);
        out[(size_t)m * Dm + n] = fmaxf(acc + bo[n], 0.0f);
    }
#endif
}

// ---------------------------------------------------------------------------
// Flash attention — byte-identical to r15 (passing); y stored swz.
// ---------------------------------------------------------------------------
__global__ __launch_bounds__(256)
void attn_fwd(const f16* __restrict__ qh, const f16* __restrict__ kh,
              const f16* __restrict__ vt, f16* __restrict__ y)
{
    const int bz = blockIdx.x;       // B*H*(S/64) = 1024
    const int qt = bz & 15;
    const int h  = (bz >> 4) & 15;
    const int b  = bz >> 8;
    const size_t head = (size_t)(b * NH + h) * S * HD;

#if USE_A16
    __shared__ alignas(16) f16 Ks[2][64][72];
    __shared__ alignas(16) f16 Vs[2][64][72];

    const int tid  = threadIdx.x;
    const int wave = tid >> 6;
    const int lane = tid & 63;
    const int l15  = lane & 15;
    const int quad = lane >> 4;
    const int sr   = tid >> 2;
    const int sc   = (tid & 3) * 16;

    const f16* Qrow = qh + head + (size_t)(qt * 64 + wave * 16 + l15) * HD;
    const f16* Kp   = kh + head;
    const f16* Vp   = vt + head;

    f16x8 aq[2];
    {
        const uint4 q0 = *(const uint4*)(Qrow + quad * 16);
        const uint4 q1 = *(const uint4*)(Qrow + quad * 16 + 8);
        aq[0] = *(f16x8*)&q0;
        aq[1] = *(f16x8*)&q1;
    }

    const int qg = qt * 64 + wave * 16 + l15;
    float m_i = -1e30f, l_i = 0.0f;
    f32x4 acc_o[4] = {};

    uint4 pk[2], pv[2];
    auto pref = [&](int kt) {
        const f16* Kr = Kp + (size_t)(kt * 64 + sr) * HD + sc;
        pk[0] = *(const uint4*)Kr;
        pk[1] = *(const uint4*)(Kr + 8);
        const f16* Vr = Vp + (size_t)sr * S + kt * 64 + sc;
        pv[0] = *(const uint4*)Vr;
        pv[1] = *(const uint4*)(Vr + 8);
    };

    pref(0);
    for (int kt = 0; kt <= qt; ++kt) {
        const int cur = kt & 1;
        *(uint4*)&Ks[cur][sr][sc]     = pk[0];
        *(uint4*)&Ks[cur][sr][sc + 8] = pk[1];
        {
            const int sb = (sc >> 4) * 4;
            *(f16x4*)&Vs[cur][sr][0 * 16 + sb] = *(f16x4*)((f16*)&pv[0]);
            *(f16x4*)&Vs[cur][sr][1 * 16 + sb] = *(f16x4*)((f16*)&pv[0] + 4);
            *(f16x4*)&Vs[cur][sr][2 * 16 + sb] = *(f16x4*)((f16*)&pv[1]);
            *(f16x4*)&Vs[cur][sr][3 * 16 + sb] = *(f16x4*)((f16*)&pv[1] + 4);
        }
        __syncthreads();
        if (kt < qt) pref(kt + 1);

        f32x4 accs[4] = {};
#pragma unroll
        for (int t = 0; t < 4; ++t) {
            const f16x8 k8a = *(const f16x8*)&Ks[cur][t * 16 + l15][quad * 16];
            const f16x8 k8b = *(const f16x8*)&Ks[cur][t * 16 + l15][quad * 16 + 8];
            MFMA16K32(accs[t], k8a, aq[0]);
            MFMA16K32(accs[t], k8b, aq[1]);
        }

        const int key0 = kt * 64 + quad * 4;
#pragma unroll
        for (int t = 0; t < 4; ++t)
#pragma unroll
            for (int r = 0; r < 4; ++r) {
                float sv = accs[t][r] * 0.125f;
                if (key0 + t * 16 + r > qg) sv = -1e9f;
                accs[t][r] = sv;
            }

        float mx = accs[0][0];
#pragma unroll
        for (int t = 0; t < 4; ++t)
#pragma unroll
            for (int r = 0; r < 4; ++r) mx = fmaxf(mx, accs[t][r]);
        mx = fmaxf(mx, __shfl_xor(mx, 16, 64));
        mx = fmaxf(mx, __shfl_xor(mx, 32, 64));
        const float mnew = fmaxf(m_i, mx);
        float sm = 0.0f;
#pragma unroll
        for (int t = 0; t < 4; ++t)
#pragma unroll
            for (int r = 0; r < 4; ++r) {
                const float e = __expf(accs[t][r] - mnew);
                accs[t][r] = e;
                sm += e;
            }
        sm += __shfl_xor(sm, 16, 64);
        sm += __shfl_xor(sm, 32, 64);
        const float alpha = __expf(m_i - mnew);
        l_i = l_i * alpha + sm;
        m_i = mnew;

        f16x4 ap[4];
#pragma unroll
        for (int c = 0; c < 4; ++c) {
            f16x4 v;
#pragma unroll
            for (int j = 0; j < 4; ++j) v[j] = (f16)accs[c][j];
            ap[c] = v;
        }

        float ar[4];
#pragma unroll
        for (int r = 0; r < 4; ++r) ar[r] = __shfl(alpha, quad * 4 + r, 64);
#pragma unroll
        for (int t2 = 0; t2 < 4; ++t2)
#pragma unroll
            for (int r = 0; r < 4; ++r) acc_o[t2][r] *= ar[r];
#pragma unroll
        for (int t2 = 0; t2 < 4; ++t2) {
            const f16x8 v8a = *(const f16x8*)&Vs[cur][t2 * 16 + l15][quad * 16];
            const f16x8 v8b = *(const f16x8*)&Vs[cur][t2 * 16 + l15][quad * 16 + 8];
            MFMA16(acc_o[t2], ap[0], LO4(v8a));
            MFMA16(acc_o[t2], ap[1], HI4(v8a));
            MFMA16(acc_o[t2], ap[2], LO4(v8b));
            MFMA16(acc_o[t2], ap[3], HI4(v8b));
        }
    }

    float lr[4];
#pragma unroll
    for (int r = 0; r < 4; ++r) lr[r] = __shfl(l_i, quad * 4 + r, 64);
#pragma unroll
    for (int t2 = 0; t2 < 4; ++t2)
#pragma unroll
        for (int r = 0; r < 4; ++r) {
            const int srow = qt * 64 + wave * 16 + quad * 4 + r;
            const int dcol = h * 64 + t2 * 16 + l15;
            y[((size_t)b * S + srow) * Dm + swz(srow, dcol)] =
                (f16)(acc_o[t2][r] / lr[r]);
        }
#else
    const int tid = threadIdx.x;
    if (tid < 64) {
        const int q = qt * 64 + tid;
        const f16* Qr = qh + head + (size_t)q * HD;
        float qv[64];
        for (int d = 0; d < 64; ++d) qv[d] = (float)Qr[pcol64(d)];
        float mx = -1e30f;
        for (int key = 0; key <= q; ++key) {
            const f16* Kr = kh + head + (size_t)key * HD;
            float s = 0.0f;
            for (int d = 0; d < 64; ++d) s = fmaf(qv[d], (float)Kr[pcol64(d)], s);
            mx = fmaxf(mx, s * 0.125f);
        }
        float o[64];
        for (int d = 0; d < 64; ++d) o[d] = 0.0f;
        float l = 0.0f;
        for (int key = 0; key <= q; ++key) {
            const f16* Kr = kh + head + (size_t)key * HD;
            float s = 0.0f;
            for (int d = 0; d < 64; ++d) s = fmaf(qv[d], (float)Kr[pcol64(d)], s);
            const float p = __expf(s * 0.125f - mx);
            l += p;
            for (int d = 0; d < 64; ++d)
                o[d] = fmaf(p, (float)vt[head + (size_t)d * S + key], o[d]);
        }
        for (int d = 0; d < 64; ++d)
            y[((size_t)b * S + q) * Dm + swz(q, h * 64 + d)] = (f16)(o[d] / l);
    }
#endif
}

// ---------------------------------------------------------------------------
// ws layout (32 MB total):
//   [0,8M)   qh
//   [8,16M)  kh
//   [16,24M) vt
//   [24,32M) Wq/Wk/Wv f16 (6MB, dead after gemm_qkv) -> y (8MB, from attn)
// (wo is consumed as fp32 directly by gemm_out — no f16 copy needed.)
// ---------------------------------------------------------------------------
extern "C" void kernel_launch(void* const* d_in, const int* in_sizes, int n_in,
                              void* d_out, int out_size, void* d_ws, size_t ws_size,
                              hipStream_t stream)
{
    f16* ws = (f16*)d_ws;
    const size_t SEG = (size_t)4 * 1024 * 1024;   // 4M f16 = 8 MB per region
    f16* qh   = ws;
    f16* kh   = ws + SEG;
    f16* vt   = ws + 2 * SEG;
    f16* wqkv = ws + 3 * SEG;   // 3M f16, dead after gemm_qkv
    f16* y    = ws + 3 * SEG;   // attn overwrites the wqkv region

    cvt_w<<<dim3(1024, 3), 256, 0, stream>>>(
        (const float*)d_in[4], (const float*)d_in[6], (const float*)d_in[8], wqkv);
    gemm_qkv<<<dim3(32, 8, 3), 512, 0, stream>>>(
        (const float*)d_in[0], (const float*)d_in[1], (const float*)d_in[2],
        wqkv,
        (const float*)d_in[5], (const float*)d_in[7], (const float*)d_in[9],
        qh, kh, vt);
    // d_in[3] = causal tril mask, hardcoded
    attn_fwd<<<dim3(4 * NH * (S / 64)), 256, 0, stream>>>(qh, kh, vt, y);
    gemm_out<<<dim3(64, 16), 256, 0, stream>>>(
        y, (const float*)d_in[10], (const float*)d_in[11], (float*)d_out);
}

// Round 8
// 238.724 us; speedup vs baseline: 1.1823x; 1.0522x over previous
//
#include <hip/hip_runtime.h>

// Round 17: attention occupancy attack (the last unprofiled big kernel).
// qkv is pinned at ~66 us across 7 structural variants (r10-r16) — exhausted.
// Total 251 = qkv 67 + cvt ~7 + attn + gemm_out + gaps; attn/out each <66
// (never in top-5) but together ~160. Attn ran at 16 waves/CU (1024 blocks x
// 4 waves, 36KB LDS -> 4 blk/CU) — lowest in the pipeline.
// Change: Q-tile 128 rows / 8 waves / 512 threads. Per-wave work identical
// (16 q-rows, same softmax, same MFMA maps); K/V staging per-thread halved
// (1 uint4 each); 512 blocks; launch_bounds(512,6) -> 3 blk/CU = 24 waves/CU.
// V-transpose store remapped for 8-col threads, re-derived against the
// verified involution col(16s+4g+j)=16g+4s+j. Causal bound kt<=2qt+1.
// gemm_qkv / gemm_out / cvt_w byte-identical to r16 (clean attribution).

using f16    = _Float16;
using f16x4  = __attribute__((ext_vector_type(4))) _Float16;
using f16x8  = __attribute__((ext_vector_type(8))) _Float16;
using f32x4  = __attribute__((ext_vector_type(4))) float;
using f32x16 = __attribute__((ext_vector_type(16))) float;

static constexpr int S = 1024, Dm = 1024, NH = 16, HD = 64;

#if __has_builtin(__builtin_amdgcn_mfma_f32_32x32x16_f16)
#define USE_G32 1
#define MFMA32(ACC, A_, B_) \
    (ACC) = __builtin_amdgcn_mfma_f32_32x32x16_f16((A_), (B_), (ACC), 0, 0, 0)
#else
#define USE_G32 0
#endif

#if __has_builtin(__builtin_amdgcn_mfma_f32_16x16x32_f16) && \
    __has_builtin(__builtin_amdgcn_mfma_f32_16x16x16f16)
#define USE_A16 1
#define MFMA16K32(ACC, A_, B_) \
    (ACC) = __builtin_amdgcn_mfma_f32_16x16x32_f16((A_), (B_), (ACC), 0, 0, 0)
#define MFMA16(ACC, A_, B_) \
    (ACC) = __builtin_amdgcn_mfma_f32_16x16x16f16((A_), (B_), (ACC), 0, 0, 0)
#else
#define USE_A16 0
#endif

#define LO4(v) __builtin_shufflevector((v), (v), 0, 1, 2, 3)
#define HI4(v) __builtin_shufflevector((v), (v), 4, 5, 6, 7)

__device__ __forceinline__ f16x4 cvt4(float4 a) {
    f16x4 r; r[0] = (f16)a.x; r[1] = (f16)a.y; r[2] = (f16)a.z; r[3] = (f16)a.w;
    return r;
}

// hd permutation for qh/kh (K=32 QK MFMA), verified round 10.
__device__ __forceinline__ int pcol64(int k) {
#if USE_A16
    return ((k >> 3) & 3) * 16 + ((k >> 5) << 3) + (k & 7);
#else
    return ((k >> 2) & 3) * 16 + ((k >> 4) << 2) + (k & 3);
#endif
}

// f16 bank swizzle for 32-f16 (64B) chunks (verified r13/r15): 16B slot (2b)
// ^= (row>>1)&3.
__device__ __forceinline__ int swz(int row, int col) {
    return (col & ~31) | ((((col >> 3) ^ (row >> 1)) & 3) << 3) | (col & 7);
}

// mode 0: [B,H,S,HD] f16 hd-permuted; 1: [B,H,HD,S] f16
__device__ __forceinline__ void store_out(void* out, int mode, int m, int n, float v) {
    const int b_ = m >> 10, s_ = m & 1023, h_ = n >> 6, hd_ = n & 63;
    const size_t idx = (mode == 0)
        ? (((size_t)(b_ * NH + h_) * S + s_) * HD + pcol64(hd_))
        : (((size_t)(b_ * NH + h_) * HD + hd_) * S + s_);
    ((f16*)out)[idx] = (f16)v;
}

#if __has_builtin(__builtin_amdgcn_global_load_lds)
#define HAS_GLL 1
#else
#define HAS_GLL 0
#endif

__device__ __forceinline__ void gll16(const void* g, void* l) {
#if HAS_GLL
    __builtin_amdgcn_global_load_lds(
        (const __attribute__((address_space(1))) void*)g,
        (__attribute__((address_space(3))) void*)l, 16, 0, 0);
#else
    *(uint4*)l = *(const uint4*)g;   // sync fallback; drained by barrier
#endif
}

// ---------------------------------------------------------------------------
// fp32 W -> f16, swz layout (verified). grid (1024, 3); one float4/thread.
// ---------------------------------------------------------------------------
__global__ __launch_bounds__(256)
void cvt_w(const float* __restrict__ s0, const float* __restrict__ s1,
           const float* __restrict__ s2, f16* __restrict__ dst)
{
    const int z = blockIdx.y;
    const float* src = (z == 0) ? s0 : (z == 1) ? s1 : s2;
    const int e = blockIdx.x * 256 + threadIdx.x;
    const int n = e >> 8;
    const int k = (e & 255) * 4;
    const float4 v = *(const float4*)(src + (size_t)n * Dm + k);
    *(f16x4*)(dst + (size_t)z * Dm * Dm + (size_t)n * Dm + swz(n, k)) = cvt4(v);
}

// ---------------------------------------------------------------------------
// gemm_qkv — byte-identical to r16 (67 us, exhausted structure).
// ---------------------------------------------------------------------------
__global__ __launch_bounds__(512, 6)
void gemm_qkv(const float* __restrict__ q, const float* __restrict__ k,
              const float* __restrict__ v, const f16* __restrict__ wqkv,
              const float* __restrict__ bq, const float* __restrict__ bk,
              const float* __restrict__ bv,
              f16* __restrict__ qh, f16* __restrict__ kh, f16* __restrict__ vt)
{
    const int z = blockIdx.z;
    const float* A = (z == 0) ? q : (z == 1) ? k : v;
    const float* bias = (z == 0) ? bq : (z == 1) ? bk : bv;
    f16* out = (z == 0) ? qh : (z == 1) ? kh : vt;
    const int mode = (z == 2) ? 1 : 0;
    const f16* Wf = wqkv + (size_t)z * Dm * Dm;

    const int tid = threadIdx.x;
    const int bm = blockIdx.x, bn = blockIdx.y;   // (32, 8)
#if USE_G32
    __shared__ alignas(16) float As[2][128][32];  // 2 x 16 KB
    __shared__ alignas(16) f16   Ws[2][128][32];  // 2 x  8 KB (48 KB total)

    const int lane = tid & 63, wave = tid >> 6;
    const int l31 = lane & 31, kh2 = lane >> 5;
    const int wm = wave & 3, wn = wave >> 2;

    const int arow = tid >> 3;
    const int aslotD = tid & 7;
    const int aslotS = aslotD ^ (arow & 7);
    const float* Asrc0 = A + (size_t)(bm * 128 + arow) * Dm + aslotS * 4;
    const int wrow = tid >> 2, wcol = (tid & 3) * 8;
    const f16* Wsrc0 = Wf + (size_t)(bn * 128 + wrow) * Dm + wcol;

    auto dma = [&](int k0, int buf) {
        gll16(Asrc0 + k0,                      &As[buf][arow][aslotD * 4]);
        gll16(Asrc0 + (size_t)64 * Dm + k0,    &As[buf][64 + arow][aslotD * 4]);
        gll16(Wsrc0 + k0,                      &Ws[buf][wrow][wcol]);
    };

    auto afrag = [&](int buf, int r, int s) -> f16x8 {
        const int p = s * 4 + kh2 * 2, r7 = r & 7;
        const f32x4 lo = *(const f32x4*)&As[buf][r][(p ^ r7) * 4];
        const f32x4 hi = *(const f32x4*)&As[buf][r][((p + 1) ^ r7) * 4];
        f16x8 f;
        f[0] = (f16)lo[0]; f[1] = (f16)lo[1]; f[2] = (f16)lo[2]; f[3] = (f16)lo[3];
        f[4] = (f16)hi[0]; f[5] = (f16)hi[1]; f[6] = (f16)hi[2]; f[7] = (f16)hi[3];
        return f;
    };
    auto wfrag = [&](int buf, int r, int s) -> f16x8 {
        const int sl = s * 2 + kh2;
        return *(const f16x8*)&Ws[buf][r][((sl ^ (r >> 1)) & 3) * 8];
    };

    f32x16 acc[2] = {};
    auto kslice = [&](int buf, int s) {
        const f16x8 af  = afrag(buf, wm * 32 + l31, s);
        const f16x8 bf0 = wfrag(buf, wn * 64 + l31, s);
        const f16x8 bf1 = wfrag(buf, wn * 64 + 32 + l31, s);
        MFMA32(acc[0], af, bf0);
        MFMA32(acc[1], af, bf1);
    };

    constexpr int NIT = Dm / 32;   // 32
    dma(0, 0);
    for (int t = 0; t < NIT; ++t) {
        const int cur = t & 1;
        __syncthreads();
        if (t + 1 < NIT) dma((t + 1) * 32, cur ^ 1);
        kslice(cur, 0);
        kslice(cur, 1);
    }

#pragma unroll
    for (int j = 0; j < 2; ++j) {
        const int col = bn * 128 + wn * 64 + j * 32 + l31;
        const float bb = bias[col];
#pragma unroll
        for (int blk = 0; blk < 4; ++blk) {
            const int row0 = bm * 128 + wm * 32 + 8 * blk + 4 * kh2;
            if (mode == 1) {
                const int b_ = row0 >> 10, s_ = row0 & 1023;
                const int h_ = col >> 6, hd_ = col & 63;
                f16x4 vv;
#pragma unroll
                for (int r = 0; r < 4; ++r)
                    vv[r] = (f16)fmaxf(acc[j][blk * 4 + r] + bb, 0.0f);
                *(f16x4*)&out[((size_t)(b_ * NH + h_) * HD + hd_) * S + s_] = vv;
            } else {
#pragma unroll
                for (int r = 0; r < 4; ++r)
                    store_out(out, mode, row0 + r, col,
                              fmaxf(acc[j][blk * 4 + r] + bb, 0.0f));
            }
        }
    }
#else
    for (int i = tid; i < 128 * 128; i += 512) {
        const int m = bm * 128 + (i >> 7);
        const int n = bn * 128 + (i & 127);
        float acc = 0.0f;
        for (int k2 = 0; k2 < Dm; ++k2)
            acc = fmaf(A[(size_t)m * Dm + k2], (float)Wf[(size_t)n * Dm + swz(n, k2)], acc);
        store_out(out, mode, m, n, fmaxf(acc + bias[n], 0.0f));
    }
#endif
}

// ---------------------------------------------------------------------------
// gemm_out — byte-identical to r16.
// ---------------------------------------------------------------------------
__global__ __launch_bounds__(256, 6)
void gemm_out(const f16* __restrict__ y, const float* __restrict__ wo,
              const float* __restrict__ bo, float* __restrict__ out)
{
    const int tid = threadIdx.x;
    const int bm = blockIdx.x, bn = blockIdx.y;   // (64, 16)
#if USE_G32
    __shared__ alignas(16) f16   As[2][64][32];
    __shared__ alignas(16) float Wsf[2][64][32];

    const int lane = tid & 63, wave = tid >> 6;
    const int l31 = lane & 31, kh2 = lane >> 5;
    const int wm = wave & 1, wn = wave >> 1;

    const int drow = tid >> 2, dcol = (tid & 3) * 8;
    const f16* Asrc = y + (size_t)(bm * 64 + drow) * Dm + dcol;
    const int wrow = tid >> 3;
    const int wslotD = tid & 7;
    const int wslotS = wslotD ^ (wrow & 7);
    const float* Wsrc0 = wo + (size_t)(bn * 64 + wrow) * Dm + wslotS * 4;

    auto dma = [&](int k0, int buf) {
        gll16(Asrc + k0, &As[buf][drow][dcol]);
        gll16(Wsrc0 + k0,                   &Wsf[buf][wrow][wslotD * 4]);
        gll16(Wsrc0 + (size_t)32 * Dm + k0, &Wsf[buf][32 + wrow][wslotD * 4]);
    };
    auto yfrag = [&](int buf, int r, int s) -> f16x8 {
        const int sl = s * 2 + kh2;
        return *(const f16x8*)&As[buf][r][((sl ^ (r >> 1)) & 3) * 8];
    };
    auto wfrag32 = [&](int buf, int r, int s) -> f16x8 {
        const int p = s * 4 + kh2 * 2, r7 = r & 7;
        const f32x4 lo = *(const f32x4*)&Wsf[buf][r][(p ^ r7) * 4];
        const f32x4 hi = *(const f32x4*)&Wsf[buf][r][((p + 1) ^ r7) * 4];
        f16x8 f;
        f[0] = (f16)lo[0]; f[1] = (f16)lo[1]; f[2] = (f16)lo[2]; f[3] = (f16)lo[3];
        f[4] = (f16)hi[0]; f[5] = (f16)hi[1]; f[6] = (f16)hi[2]; f[7] = (f16)hi[3];
        return f;
    };

    f32x16 acc = {};
    constexpr int NIT = Dm / 32;   // 32
    dma(0, 0);
    for (int t = 0; t < NIT; ++t) {
        const int cur = t & 1;
        __syncthreads();
        if (t + 1 < NIT) dma((t + 1) * 32, cur ^ 1);
#pragma unroll
        for (int s = 0; s < 2; ++s) {
            const f16x8 af = yfrag(cur, wm * 32 + l31, s);
            const f16x8 bf = wfrag32(cur, wn * 32 + l31, s);
            MFMA32(acc, af, bf);
        }
    }

    const int col = bn * 64 + wn * 32 + l31;
    const float bb = bo[col];
#pragma unroll
    for (int blk = 0; blk < 4; ++blk) {
        const int row0 = bm * 64 + wm * 32 + 8 * blk + 4 * kh2;
#pragma unroll
        for (int r = 0; r < 4; ++r)
            out[(size_t)(row0 + r) * Dm + col] = fmaxf(acc[blk * 4 + r] + bb, 0.0f);
    }
#else
    for (int i = tid; i < 64 * 64; i += 256) {
        const int m = bm * 64 + (i >> 6);
        const int n = bn * 64 + (i & 63);
        float acc = 0.0f;
        for (int k2 = 0; k2 < Dm; ++k2)
            acc = fmaf((float)y[(size_t)m * Dm + swz(m, k2)],
                       wo[(size_t)n * Dm + k2], acc);
        out[(size_t)m * Dm + n] = fmaxf(acc + bo[n], 0.0f);
    }
#endif
}

// ---------------------------------------------------------------------------
// Flash attention — 128-row Q tile, 8 waves (512 thr), 24 waves/CU.
// Per-wave math identical to the verified r10-r16 kernel (16 q-rows, S^T
// trick, K32 QK, K16 PV, same softmax). Staging: 512 threads, 16B each:
//   K: Ks[cur][sr][t8*8] <- K[kt*64+sr][t8*8..+7]        (sr=tid>>3, t8=tid&7)
//   V: key K=8*t8+e at col(16s+4g+j)=16g+4s+j (verified involution):
//      elems 0-3 -> col 16*((2t8)&3)+4*(t8>>1); elems 4-7 -> +16 group.
// Causal: ktmax = 2*qt+1; per-row masking via qg (unchanged).
// ---------------------------------------------------------------------------
__global__ __launch_bounds__(512, 6)
void attn_fwd(const f16* __restrict__ qh, const f16* __restrict__ kh,
              const f16* __restrict__ vt, f16* __restrict__ y)
{
    const int bz = blockIdx.x;       // B*H*(S/128) = 512
    const int qt = bz & 7;
    const int h  = (bz >> 3) & 15;
    const int b  = bz >> 7;
    const size_t head = (size_t)(b * NH + h) * S * HD;

#if USE_A16
    __shared__ alignas(16) f16 Ks[2][64][72];
    __shared__ alignas(16) f16 Vs[2][64][72];

    const int tid  = threadIdx.x;
    const int wave = tid >> 6;       // 0..7
    const int lane = tid & 63;
    const int l15  = lane & 15;
    const int quad = lane >> 4;
    const int sr   = tid >> 3;       // 0..63
    const int t8   = tid & 7;        // 8B-col group

    const f16* Qrow = qh + head + (size_t)(qt * 128 + wave * 16 + l15) * HD;
    const f16* Kp   = kh + head;
    const f16* Vp   = vt + head;

    f16x8 aq[2];
    {
        const uint4 q0 = *(const uint4*)(Qrow + quad * 16);
        const uint4 q1 = *(const uint4*)(Qrow + quad * 16 + 8);
        aq[0] = *(f16x8*)&q0;
        aq[1] = *(f16x8*)&q1;
    }

    const int qg = qt * 128 + wave * 16 + l15;
    float m_i = -1e30f, l_i = 0.0f;
    f32x4 acc_o[4] = {};

    // V store columns (verified involution)
    const int vc0 = 16 * ((2 * t8) & 3) + 4 * (t8 >> 1);
    const int vc1 = 16 * ((2 * t8 + 1) & 3) + 4 * (t8 >> 1);

    uint4 pk, pv;
    auto pref = [&](int kt) {
        pk = *(const uint4*)(Kp + (size_t)(kt * 64 + sr) * HD + t8 * 8);
        pv = *(const uint4*)(Vp + (size_t)sr * S + kt * 64 + t8 * 8);
    };

    const int ktmax = 2 * qt + 1;
    pref(0);
    for (int kt = 0; kt <= ktmax; ++kt) {
        const int cur = kt & 1;
        *(uint4*)&Ks[cur][sr][t8 * 8] = pk;
        {
            f16x8 pv8 = *(f16x8*)&pv;
            *(f16x4*)&Vs[cur][sr][vc0] = LO4(pv8);
            *(f16x4*)&Vs[cur][sr][vc1] = HI4(pv8);
        }
        __syncthreads();
        if (kt < ktmax) pref(kt + 1);

        f32x4 accs[4] = {};
#pragma unroll
        for (int t = 0; t < 4; ++t) {
            const f16x8 k8a = *(const f16x8*)&Ks[cur][t * 16 + l15][quad * 16];
            const f16x8 k8b = *(const f16x8*)&Ks[cur][t * 16 + l15][quad * 16 + 8];
            MFMA16K32(accs[t], k8a, aq[0]);
            MFMA16K32(accs[t], k8b, aq[1]);
        }

        const int key0 = kt * 64 + quad * 4;
#pragma unroll
        for (int t = 0; t < 4; ++t)
#pragma unroll
            for (int r = 0; r < 4; ++r) {
                float sv = accs[t][r] * 0.125f;
                if (key0 + t * 16 + r > qg) sv = -1e9f;
                accs[t][r] = sv;
            }

        float mx = accs[0][0];
#pragma unroll
        for (int t = 0; t < 4; ++t)
#pragma unroll
            for (int r = 0; r < 4; ++r) mx = fmaxf(mx, accs[t][r]);
        mx = fmaxf(mx, __shfl_xor(mx, 16, 64));
        mx = fmaxf(mx, __shfl_xor(mx, 32, 64));
        const float mnew = fmaxf(m_i, mx);
        float sm = 0.0f;
#pragma unroll
        for (int t = 0; t < 4; ++t)
#pragma unroll
            for (int r = 0; r < 4; ++r) {
                const float e = __expf(accs[t][r] - mnew);
                accs[t][r] = e;
                sm += e;
            }
        sm += __shfl_xor(sm, 16, 64);
        sm += __shfl_xor(sm, 32, 64);
        const float alpha = __expf(m_i - mnew);
        l_i = l_i * alpha + sm;
        m_i = mnew;

        f16x4 ap[4];
#pragma unroll
        for (int c = 0; c < 4; ++c) {
            f16x4 v;
#pragma unroll
            for (int j = 0; j < 4; ++j) v[j] = (f16)accs[c][j];
            ap[c] = v;
        }

        float ar[4];
#pragma unroll
        for (int r = 0; r < 4; ++r) ar[r] = __shfl(alpha, quad * 4 + r, 64);
#pragma unroll
        for (int t2 = 0; t2 < 4; ++t2)
#pragma unroll
            for (int r = 0; r < 4; ++r) acc_o[t2][r] *= ar[r];
#pragma unroll
        for (int t2 = 0; t2 < 4; ++t2) {
            const f16x8 v8a = *(const f16x8*)&Vs[cur][t2 * 16 + l15][quad * 16];
            const f16x8 v8b = *(const f16x8*)&Vs[cur][t2 * 16 + l15][quad * 16 + 8];
            MFMA16(acc_o[t2], ap[0], LO4(v8a));
            MFMA16(acc_o[t2], ap[1], HI4(v8a));
            MFMA16(acc_o[t2], ap[2], LO4(v8b));
            MFMA16(acc_o[t2], ap[3], HI4(v8b));
        }
    }

    float lr[4];
#pragma unroll
    for (int r = 0; r < 4; ++r) lr[r] = __shfl(l_i, quad * 4 + r, 64);
#pragma unroll
    for (int t2 = 0; t2 < 4; ++t2)
#pragma unroll
        for (int r = 0; r < 4; ++r) {
            const int srow = qt * 128 + wave * 16 + quad * 4 + r;
            const int dcol = h * 64 + t2 * 16 + l15;
            y[((size_t)b * S + srow) * Dm + swz(srow, dcol)] =
                (f16)(acc_o[t2][r] / lr[r]);
        }
#else
    const int tid = threadIdx.x;
    if (tid < 128) {
        const int q = qt * 128 + tid;
        const f16* Qr = qh + head + (size_t)q * HD;
        float qv[64];
        for (int d = 0; d < 64; ++d) qv[d] = (float)Qr[pcol64(d)];
        float mx = -1e30f;
        for (int key = 0; key <= q; ++key) {
            const f16* Kr = kh + head + (size_t)key * HD;
            float s = 0.0f;
            for (int d = 0; d < 64; ++d) s = fmaf(qv[d], (float)Kr[pcol64(d)], s);
            mx = fmaxf(mx, s * 0.125f);
        }
        float o[64];
        for (int d = 0; d < 64; ++d) o[d] = 0.0f;
        float l = 0.0f;
        for (int key = 0; key <= q; ++key) {
            const f16* Kr = kh + head + (size_t)key * HD;
            float s = 0.0f;
            for (int d = 0; d < 64; ++d) s = fmaf(qv[d], (float)Kr[pcol64(d)], s);
            const float p = __expf(s * 0.125f - mx);
            l += p;
            for (int d = 0; d < 64; ++d)
                o[d] = fmaf(p, (float)vt[head + (size_t)d * S + key], o[d]);
        }
        for (int d = 0; d < 64; ++d)
            y[((size_t)b * S + q) * Dm + swz(q, h * 64 + d)] = (f16)(o[d] / l);
    }
#endif
}

// ---------------------------------------------------------------------------
// ws layout (32 MB total):
//   [0,8M)   qh
//   [8,16M)  kh
//   [16,24M) vt
//   [24,32M) Wq/Wk/Wv f16 (6MB, dead after gemm_qkv) -> y (8MB, from attn)
// ---------------------------------------------------------------------------
extern "C" void kernel_launch(void* const* d_in, const int* in_sizes, int n_in,
                              void* d_out, int out_size, void* d_ws, size_t ws_size,
                              hipStream_t stream)
{
    f16* ws = (f16*)d_ws;
    const size_t SEG = (size_t)4 * 1024 * 1024;   // 4M f16 = 8 MB per region
    f16* qh   = ws;
    f16* kh   = ws + SEG;
    f16* vt   = ws + 2 * SEG;
    f16* wqkv = ws + 3 * SEG;   // 3M f16, dead after gemm_qkv
    f16* y    = ws + 3 * SEG;   // attn overwrites the wqkv region

    cvt_w<<<dim3(1024, 3), 256, 0, stream>>>(
        (const float*)d_in[4], (const float*)d_in[6], (const float*)d_in[8], wqkv);
    gemm_qkv<<<dim3(32, 8, 3), 512, 0, stream>>>(
        (const float*)d_in[0], (const float*)d_in[1], (const float*)d_in[2],
        wqkv,
        (const float*)d_in[5], (const float*)d_in[7], (const float*)d_in[9],
        qh, kh, vt);
    // d_in[3] = causal tril mask, hardcoded
    attn_fwd<<<dim3(4 * NH * (S / 128)), 512, 0, stream>>>(qh, kh, vt, y);
    gemm_out<<<dim3(64, 16), 256, 0, stream>>>(
        y, (const float*)d_in[10], (const float*)d_in[11], (float*)d_out);
}